// Round 10
// baseline (595.718 us; speedup 1.0000x reference)
//
#include <hip/hip_runtime.h>
#include <hip/hip_bf16.h>
#include <hip/hip_fp16.h>
#include <math.h>

#define NPROJ 1024
#define NHEADS 4
#define NHID 256
#define NGRAPH 64

typedef _Float16 half8 __attribute__((ext_vector_type(8)));
typedef _Float16 half4v __attribute__((ext_vector_type(4)));
typedef float floatx4 __attribute__((ext_vector_type(4)));

#define GLD_LDS16(g, l)                                                        \
  __builtin_amdgcn_global_load_lds(                                            \
      (const __attribute__((address_space(1))) unsigned int*)(g),              \
      (__attribute__((address_space(3))) unsigned int*)(l), 16, 0, 0)

// ============================================================
// Single-product f16 MFMA GEMM:  C = A @ BT^T   (K fixed = 1024)
// A: M x 1024 f16 (hi of fp32).  B TRANSPOSED: Nc x 1024 f16 (hi of fp32).
// 128x128 tile, BK=64, 4 waves (2x2), wave 64x64, 16x16x32 MFMA.
// LDS = 2 x 16KB = 32KB -> 4 blocks/CU; grid 640 fits one residency round.
// Single-buffer overlap: frags->regs, barrier, STAGE(t+1) under MFMAs.
// XOR-swizzled LDS via pre-swizzled global source.
// XCD-chunked grid: each XCD owns mpad8 contiguous row-slabs, bx fastest.
// OUT==2 additionally fuses the GAT attention logits: each wave's 128-col
// slice lies in ONE head (hd=n0>>8); per-row partial dots vs a_src/a_dst
// reduce over the 16-lane row group (shfl_xor) then atomicAdd into
// as_out/ad_out (zeroed per layer) -- removes the k_alpha full re-read of h.
// ============================================================
template<int ACT, int OUT>  // ACT: 0 none, 1 tanh; OUT: 0 f32, 1 split pair, 2 f16
__global__ __launch_bounds__(256, 4) void gemm_mfma(
    const _Float16* __restrict__ A, const _Float16* __restrict__ BT,
    const float* __restrict__ bias, float* __restrict__ Cf,
    _Float16* __restrict__ Ch, _Float16* __restrict__ Cl,
    const float* __restrict__ a_src, const float* __restrict__ a_dst,
    float* __restrict__ as_out, float* __restrict__ ad_out,
    int M, int Nc, int lgn, int mpad8)
{
  __shared__ __align__(16) _Float16 ldsA[128 * 64];
  __shared__ __align__(16) _Float16 ldsB[128 * 64];

  const int id  = blockIdx.x;
  const int xcd = id & 7;
  const int kk  = id >> 3;
  const int bx  = kk & ((1 << lgn) - 1);
  const int by  = xcd * mpad8 + (kk >> lgn);
  const int m0  = by * 128, n0 = bx * 128;
  if (m0 >= M) return;

  const int tid  = threadIdx.x;
  const int lane = tid & 63;
  const int wave = tid >> 6;
  const int wm = wave >> 1, wn = wave & 1;

  const int srow = tid >> 3;                              // + r*32
  const int kc8  = (((tid & 7) ^ ((tid >> 3) & 7)) << 3); // logical k elems
  const int wb16 = (tid & ~63) * 16;                      // wave-uniform base

  floatx4 acc[4][4] = {};

  const int l15 = lane & 15;
  const int swz = (l15 & 7) << 4;
  const int kbyte0 = (lane >> 4) * 16;

  auto STAGE = [&](int t) {
    const int k0 = t << 6;
#pragma unroll
    for (int r = 0; r < 4; ++r) {
      int rowA = m0 + r * 32 + srow;
      rowA = rowA < M ? rowA : (M - 1);
      GLD_LDS16(A + (size_t)rowA * 1024 + k0 + kc8,
                (char*)ldsA + r * 4096 + wb16);
      GLD_LDS16(BT + (size_t)(n0 + r * 32 + srow) * 1024 + k0 + kc8,
                (char*)ldsB + r * 4096 + wb16);
    }
  };

  STAGE(0);
  __syncthreads();

  for (int t = 0; t < 16; ++t) {
    const int koff0 = kbyte0 ^ swz;
    half8 a0[4], b0[4];
#pragma unroll
    for (int i = 0; i < 4; ++i)
      a0[i] = *(const half8*)((const char*)ldsA +
                              (wm * 64 + i * 16 + l15) * 128 + koff0);
#pragma unroll
    for (int j = 0; j < 4; ++j)
      b0[j] = *(const half8*)((const char*)ldsB +
                              (wn * 64 + j * 16 + l15) * 128 + koff0);
#pragma unroll
    for (int i = 0; i < 4; ++i)
#pragma unroll
      for (int j = 0; j < 4; ++j)
        acc[i][j] = __builtin_amdgcn_mfma_f32_16x16x32_f16(a0[i], b0[j],
                                                           acc[i][j], 0, 0, 0);

    const int koff1 = (64 + kbyte0) ^ swz;
    half8 a1[4], b1[4];
#pragma unroll
    for (int i = 0; i < 4; ++i)
      a1[i] = *(const half8*)((const char*)ldsA +
                              (wm * 64 + i * 16 + l15) * 128 + koff1);
#pragma unroll
    for (int j = 0; j < 4; ++j)
      b1[j] = *(const half8*)((const char*)ldsB +
                              (wn * 64 + j * 16 + l15) * 128 + koff1);
    __syncthreads();            // all LDS reads of tile t complete (regs held)
    if (t < 15) STAGE(t + 1);   // overwrite LDS under the MFMAs below

#pragma unroll
    for (int i = 0; i < 4; ++i)
#pragma unroll
      for (int j = 0; j < 4; ++j)
        acc[i][j] = __builtin_amdgcn_mfma_f32_16x16x32_f16(a1[i], b1[j],
                                                           acc[i][j], 0, 0, 0);

    if (t < 15) __syncthreads();  // vmcnt drain (mostly hidden by MFMAs)
  }

  const int rbase = (lane >> 4) * 4;

  // ---- fused attention logits (GAT layers only) ----
  if (OUT == 2) {
    const int hd = n0 >> 8;   // whole 128-col block lies in one head
    float sc[4], dc[4];
#pragma unroll
    for (int j = 0; j < 4; ++j) {
      const int col = n0 + wn * 64 + j * 16 + l15;
      sc[j] = a_src[col];
      dc[j] = a_dst[col];
    }
#pragma unroll
    for (int i = 0; i < 4; ++i) {
      float ps4[4] = {}, pd4[4] = {};
#pragma unroll
      for (int j = 0; j < 4; ++j)
#pragma unroll
        for (int r = 0; r < 4; ++r) {
          ps4[r] = fmaf(acc[i][j][r], sc[j], ps4[r]);
          pd4[r] = fmaf(acc[i][j][r], dc[j], pd4[r]);
        }
#pragma unroll
      for (int r = 0; r < 4; ++r) {
        float s = ps4[r], d = pd4[r];
#pragma unroll
        for (int off = 1; off <= 8; off <<= 1) {
          s += __shfl_xor(s, off);
          d += __shfl_xor(d, off);
        }
        const int gm = m0 + wm * 64 + i * 16 + rbase + r;
        if (l15 == 0 && gm < M) {
          atomicAdd(as_out + gm * 4 + hd, s);
          atomicAdd(ad_out + gm * 4 + hd, d);
        }
      }
    }
  }

  // epilogue: C[row = (lane>>4)*4 + reg, col = lane&15] per 16x16 frag
#pragma unroll
  for (int j = 0; j < 4; ++j) {
    const int col = n0 + wn * 64 + j * 16 + l15;
    const float bv = bias ? bias[col] : 0.f;
#pragma unroll
    for (int i = 0; i < 4; ++i) {
      const int gm0 = m0 + wm * 64 + i * 16 + rbase;
#pragma unroll
      for (int r = 0; r < 4; ++r) {
        const int gm = gm0 + r;
        if (gm >= M) continue;
        float v = acc[i][j][r] + bv;
        if (ACT == 1) v = tanhf(v);
        if (OUT == 1) {
          _Float16 hh = (_Float16)v;
          Ch[(size_t)gm * Nc + col] = hh;
          Cl[(size_t)gm * Nc + col] = (_Float16)(v - (float)hh);
        } else if (OUT == 2) {
          Ch[(size_t)gm * Nc + col] = (_Float16)v;
        } else {
          Cf[(size_t)gm * Nc + col] = v;
        }
      }
    }
  }
}

// ============================================================
// converters
// ============================================================
__global__ void k_tof16(const float* __restrict__ in, _Float16* __restrict__ h,
                        int L8) {
  int i = blockIdx.x * 256 + threadIdx.x;
  if (i >= L8) return;
  const float4* p = (const float4*)(in + (size_t)i * 8);
  float4 v0 = p[0], v1 = p[1];
  float vv[8] = {v0.x, v0.y, v0.z, v0.w, v1.x, v1.y, v1.z, v1.w};
  half8 hv;
#pragma unroll
  for (int j = 0; j < 8; ++j) hv[j] = (_Float16)vv[j];
  *(half8*)(h + (size_t)i * 8) = hv;
}

// W (K x Nc) fp32 -> transposed (Nc x K) f16
__global__ __launch_bounds__(256) void k_transT(const float* __restrict__ in,
                                                _Float16* __restrict__ hT,
                                                int K, int Nc) {
  __shared__ float t[32][33];
  const int tx = threadIdx.x & 31, ty = threadIdx.x >> 5;
  const int c0 = blockIdx.x * 32, k0 = blockIdx.y * 32;
#pragma unroll
  for (int r = 0; r < 4; ++r)
    t[ty + 8 * r][tx] = in[(size_t)(k0 + ty + 8 * r) * Nc + c0 + tx];
  __syncthreads();
#pragma unroll
  for (int r = 0; r < 4; ++r) {
    float v = t[tx][ty + 8 * r];
    int oc = c0 + ty + 8 * r;
    hT[(size_t)oc * K + k0 + tx] = (_Float16)v;
  }
}

// ============================================================
// CSR-by-dst construction (recomputed every call; no caching)
// ============================================================
__global__ void k_init_counts(int* cnt, int n) {
  int i = blockIdx.x * 256 + threadIdx.x;
  if (i < n) cnt[i] = 1;  // self-loop pre-counted
}

__global__ void k_count(const int* __restrict__ dst, int* cnt, int e) {
  int i = blockIdx.x * 256 + threadIdx.x;
  if (i < e) atomicAdd(&cnt[dst[i]], 1);
}

__global__ __launch_bounds__(1024) void k_scan(const int* __restrict__ cnt,
                                               int* __restrict__ rowstart,
                                               int* __restrict__ cursor, int n) {
  __shared__ int buf[1024];
  __shared__ int carry;
  int t = threadIdx.x;
  if (t == 0) carry = 0;
  __syncthreads();
  for (int base = 0; base < n; base += 1024) {
    int x = (base + t < n) ? cnt[base + t] : 0;
    buf[t] = x;
    __syncthreads();
    for (int off = 1; off < 1024; off <<= 1) {
      int v = (t >= off) ? buf[t - off] : 0;
      __syncthreads();
      buf[t] += v;
      __syncthreads();
    }
    int c0 = carry;
    int excl = buf[t] - x + c0;
    if (base + t < n) { rowstart[base + t] = excl; cursor[base + t] = excl; }
    __syncthreads();
    if (t == 0) carry = c0 + buf[1023];
    __syncthreads();
  }
  if (t == 0) rowstart[n] = carry;
}

__global__ void k_fill(const int* __restrict__ src, const int* __restrict__ dst,
                       int* cursor, int* __restrict__ col, int e) {
  int i = blockIdx.x * 256 + threadIdx.x;
  if (i < e) {
    int p = atomicAdd(&cursor[dst[i]], 1);
    col[p] = src[i];
  }
}

__global__ void k_fill_self(int* cursor, int* __restrict__ col, int n) {
  int i = blockIdx.x * 256 + threadIdx.x;
  if (i < n) {
    int p = atomicAdd(&cursor[i], 1);
    col[p] = i;
  }
}

// ============================================================
// fused segment-softmax + aggregation + bias/ELU/residual/LayerNorm
// (r8 form: wave wv owns head wv's 256 cols; in-wave shfl softmax;
//  short serial gather, 20 VGPR, high occupancy)
// ============================================================
__device__ __forceinline__ float lrelu02(float x) {
  return x > 0.f ? x : 0.2f * x;
}

__global__ __launch_bounds__(256) void k_aggregate_ln(
    const _Float16* __restrict__ h, const float* __restrict__ as_,
    const float* __restrict__ ad_, const int* __restrict__ rowstart,
    const int* __restrict__ col, const float* __restrict__ bias,
    const float* __restrict__ gamma, const float* __restrict__ beta,
    _Float16* __restrict__ xh, _Float16* __restrict__ xl) {
  __shared__ float sred[8];

  const int n = blockIdx.x, t = threadIdx.x;
  const int wv = t >> 6, l = t & 63;
  const int rs = rowstart[n], re = rowstart[n + 1];
  const float adn = ad_[n * 4 + wv];

  // pass 1: per-head max (in-wave)
  float mx = -1e30f;
  for (int e = rs + l; e < re; e += 64)
    mx = fmaxf(mx, lrelu02(as_[(size_t)col[e] * 4 + wv] + adn));
#pragma unroll
  for (int off = 32; off > 0; off >>= 1)
    mx = fmaxf(mx, __shfl_xor(mx, off));

  // pass 2: sum of exp (in-wave)
  float sm = 0.f;
  for (int e = rs + l; e < re; e += 64)
    sm += expf(lrelu02(as_[(size_t)col[e] * 4 + wv] + adn) - mx);
#pragma unroll
  for (int off = 32; off > 0; off >>= 1)
    sm += __shfl_xor(sm, off);
  const float Sinv = 1.f / (sm + 1e-16f);

  // pass 3: gather; lane owns cols wv*256 + 4l .. +3
  const int cb = wv * 256 + 4 * l;
  float acc[4] = {0.f, 0.f, 0.f, 0.f};
  for (int c0 = rs; c0 < re; c0 += 64) {
    const int idx = c0 + l;
    float w_l = 0.f;
    int s_l = 0;
    if (idx < re) {
      s_l = col[idx];
      w_l = expf(lrelu02(as_[(size_t)s_l * 4 + wv] + adn) - mx) * Sinv;
    }
    const int cnt = min(64, re - c0);
    for (int e = 0; e < cnt; ++e) {
      const float w = __shfl(w_l, e);
      const int s = __shfl(s_l, e);
      half4v hv = *(const half4v*)(h + (size_t)s * NPROJ + cb);
      acc[0] = fmaf(w, (float)hv[0], acc[0]);
      acc[1] = fmaf(w, (float)hv[1], acc[1]);
      acc[2] = fmaf(w, (float)hv[2], acc[2]);
      acc[3] = fmaf(w, (float)hv[3], acc[3]);
    }
  }

  // epilogue: bias, ELU, residual; LayerNorm stats
  const size_t base = (size_t)n * NPROJ + cb;
  float4 b4 = *(const float4*)(bias + cb);
  float bb[4] = {b4.x, b4.y, b4.z, b4.w};
  half4v xhv = *(const half4v*)(xh + base);
  half4v xlv = *(const half4v*)(xl + base);
  float v[4];
  float sum = 0.f, sumsq = 0.f;
#pragma unroll
  for (int j = 0; j < 4; ++j) {
    float u = acc[j] + bb[j];
    u = u > 0.f ? u : expm1f(u);
    u += (float)xhv[j] + (float)xlv[j];
    v[j] = u;
    sum += u;
    sumsq += u * u;
  }
#pragma unroll
  for (int off = 32; off > 0; off >>= 1) {
    sum += __shfl_xor(sum, off);
    sumsq += __shfl_xor(sumsq, off);
  }
  if (l == 0) {
    sred[wv] = sum;
    sred[4 + wv] = sumsq;
  }
  __syncthreads();
  const float tsum = sred[0] + sred[1] + sred[2] + sred[3];
  const float tssq = sred[4] + sred[5] + sred[6] + sred[7];
  const float mu = tsum * (1.f / 1024.f);
  const float var = tssq * (1.f / 1024.f) - mu * mu;
  const float rstd = rsqrtf(var + 1e-5f);

  float4 g4 = *(const float4*)(gamma + cb);
  float4 e4 = *(const float4*)(beta + cb);
  float gg[4] = {g4.x, g4.y, g4.z, g4.w};
  float ee[4] = {e4.x, e4.y, e4.z, e4.w};
  half4v oh, ol;
#pragma unroll
  for (int j = 0; j < 4; ++j) {
    float y = (v[j] - mu) * rstd * gg[j] + ee[j];
    _Float16 hh = (_Float16)y;
    oh[j] = hh;
    ol[j] = (_Float16)(y - (float)hh);
  }
  *(half4v*)(xh + base) = oh;
  *(half4v*)(xl + base) = ol;
}

// ============================================================
// pooling + classifier
// ============================================================
__global__ void k_scores(const float* __restrict__ tb,
                         const float* __restrict__ W2,
                         const float* __restrict__ b2,
                         float* __restrict__ scores, int N) {
  int n = blockIdx.x, lane = threadIdx.x;
  float s = 0.f;
  for (int k = lane; k < 512; k += 64) s = fmaf(tb[(size_t)n * 512 + k], W2[k], s);
  for (int off = 32; off > 0; off >>= 1) s += __shfl_down(s, off);
  if (lane == 0) scores[n] = s + b2[0];
}

__global__ void k_grange_init(int* gstart, int* gend, int N) {
  int g = threadIdx.x;
  if (g < NGRAPH) { gstart[g] = N; gend[g] = 0; }
}

__global__ void k_grange_mark(const int* __restrict__ batch, int* gstart,
                              int* gend, int N) {
  int n = blockIdx.x * 256 + threadIdx.x;
  if (n >= N) return;
  int b = batch[n];
  if (n == 0 || batch[n - 1] != b) gstart[b] = n;
  if (n == N - 1 || batch[n + 1] != b) gend[b] = n + 1;
}

__global__ __launch_bounds__(256) void k_pool(
    const float* __restrict__ scores, const _Float16* __restrict__ xh,
    const _Float16* __restrict__ xl, const int* __restrict__ gstart,
    const int* __restrict__ gend, float* __restrict__ pooled) {
  __shared__ float red[256];
  __shared__ float wt[256];
  __shared__ float m_s, s_s;
  int g = blockIdx.x, t = threadIdx.x;
  int rs = gstart[g], re = gend[g];

  float mx = -1e30f;
  for (int i = rs + t; i < re; i += 256) mx = fmaxf(mx, scores[i]);
  red[t] = mx;
  __syncthreads();
  for (int s = 128; s > 0; s >>= 1) {
    if (t < s) red[t] = fmaxf(red[t], red[t + s]);
    __syncthreads();
  }
  if (t == 0) m_s = red[0];
  __syncthreads();
  float m = m_s;

  float sm = 0.f;
  for (int i = rs + t; i < re; i += 256) sm += expf(scores[i] - m);
  red[t] = sm;
  __syncthreads();
  for (int s = 128; s > 0; s >>= 1) {
    if (t < s) red[t] += red[t + s];
    __syncthreads();
  }
  if (t == 0) s_s = red[0] + 1e-16f;
  __syncthreads();
  float sden = s_s;

  float acc[4] = {0.f, 0.f, 0.f, 0.f};
  for (int c0 = rs; c0 < re; c0 += 256) {
    int cnt = min(256, re - c0);
    if (t < cnt) wt[t] = expf(scores[c0 + t] - m) / sden;
    __syncthreads();
    for (int e = 0; e < cnt; ++e) {
      float w = wt[e];
      size_t base = (size_t)(c0 + e) * NPROJ + 4 * t;
      half4v hv = *(const half4v*)(xh + base);
      half4v lv = *(const half4v*)(xl + base);
#pragma unroll
      for (int j = 0; j < 4; ++j)
        acc[j] = fmaf(w, (float)hv[j] + (float)lv[j], acc[j]);
    }
    __syncthreads();
  }
#pragma unroll
  for (int j = 0; j < 4; ++j) pooled[(size_t)g * NPROJ + 4 * t + j] = acc[j];
}

__global__ __launch_bounds__(256) void k_cls1(const float* __restrict__ pooled,
                                              const float* __restrict__ W1,
                                              const float* __restrict__ b1,
                                              float* __restrict__ hid) {
  __shared__ float p[1024];
  int g = blockIdx.y;
  int colc = blockIdx.x * 256 + threadIdx.x;
  for (int k = threadIdx.x; k < 1024; k += 256) p[k] = pooled[(size_t)g * 1024 + k];
  __syncthreads();
  float s = 0.f;
  for (int k = 0; k < 1024; ++k) s = fmaf(p[k], W1[(size_t)k * 512 + colc], s);
  s += b1[colc];
  s = 0.5f * s * (1.f + erff(s * 0.70710678118654752f));
  hid[(size_t)g * 512 + colc] = s;
}

__global__ void k_cls2(const float* __restrict__ hid,
                       const float* __restrict__ W2,
                       const float* __restrict__ b2, float* __restrict__ out) {
  int o = blockIdx.x, g = blockIdx.y, lane = threadIdx.x;
  float s = 0.f;
  for (int k = lane; k < 512; k += 64) s = fmaf(hid[(size_t)g * 512 + k], W2[k * 14 + o], s);
  for (int off = 32; off > 0; off >>= 1) s += __shfl_down(s, off);
  if (lane == 0) out[g * 14 + o] = s + b2[o];
}

// ============================================================
extern "C" void kernel_launch(void* const* d_in, const int* in_sizes, int n_in,
                              void* d_out, int out_size, void* d_ws, size_t ws_size,
                              hipStream_t stream) {
  const float* x_in   = (const float*)d_in[0];
  const int*   eidx   = (const int*)d_in[1];
  const int*   batch  = (const int*)d_in[2];
  const float* proj_W = (const float*)d_in[3];
  const float* proj_b = (const float*)d_in[4];
  const float* gat_W  = (const float*)d_in[5];
  const float* a_src  = (const float*)d_in[6];
  const float* a_dst  = (const float*)d_in[7];
  const float* gat_b  = (const float*)d_in[8];
  const float* gamma  = (const float*)d_in[9];
  const float* beta   = (const float*)d_in[10];
  const float* pW1    = (const float*)d_in[11];
  const float* pb1    = (const float*)d_in[12];
  const float* pW2    = (const float*)d_in[13];
  const float* pb2    = (const float*)d_in[14];
  const float* cW1    = (const float*)d_in[15];
  const float* cb1    = (const float*)d_in[16];
  const float* cW2    = (const float*)d_in[17];
  const float* cb2    = (const float*)d_in[18];
  float* out = (float*)d_out;

  const int N = in_sizes[0] / NPROJ;  // 10000
  const int E = in_sizes[1] / 2;      // 160000
  const int Etot = E + N;

  char* ws = (char*)d_ws;
  size_t off = 0;
  auto alloc = [&](size_t bytes) -> void* {
    void* p = ws + off;
    off = (off + bytes + 255) & ~(size_t)255;
    return p;
  };
  _Float16* xh   = (_Float16*)alloc((size_t)N * NPROJ * 2);
  _Float16* xl   = (_Float16*)alloc((size_t)N * NPROJ * 2);
  _Float16* hf   = (_Float16*)alloc((size_t)N * NPROJ * 2);   // f16 h
  float*    hb   = (float*)alloc((size_t)N * NPROJ * 4);      // in-f16 / tb
  _Float16* pjh  = (_Float16*)alloc((size_t)NPROJ * NPROJ * 2);
  _Float16* gwh  = (_Float16*)alloc((size_t)3 * NPROJ * NPROJ * 2);
  _Float16* pwh  = (_Float16*)alloc((size_t)512 * NPROJ * 2);
  float* asb     = (float*)alloc((size_t)N * 4 * 4);
  float* adb     = (float*)alloc((size_t)N * 4 * 4);
  int*   cnt     = (int*)alloc((size_t)N * 4);
  int*   rowst   = (int*)alloc((size_t)(N + 1) * 4);
  int*   cursor  = (int*)alloc((size_t)N * 4);
  int*   ccol    = (int*)alloc((size_t)Etot * 4);
  float* scores  = (float*)alloc((size_t)N * 4);
  int*   gstart  = (int*)alloc(NGRAPH * 4);
  int*   gend    = (int*)alloc(NGRAPH * 4);
  float* pooled  = (float*)alloc((size_t)NGRAPH * NPROJ * 4);
  float* hid     = (float*)alloc((size_t)NGRAPH * 512 * 4);

  const int* esrc = eidx;
  const int* edst = eidx + E;

  // ---- CSR by dst ----
  k_init_counts<<<(N + 255) / 256, 256, 0, stream>>>(cnt, N);
  k_count<<<(E + 255) / 256, 256, 0, stream>>>(edst, cnt, E);
  k_scan<<<1, 1024, 0, stream>>>(cnt, rowst, cursor, N);
  k_fill<<<(E + 255) / 256, 256, 0, stream>>>(esrc, edst, cursor, ccol, E);
  k_fill_self<<<(N + 255) / 256, 256, 0, stream>>>(cursor, ccol, N);

  // ---- weight transposes (f16 hi) ----
  k_transT<<<dim3(32, 32), 256, 0, stream>>>(proj_W, pjh, NPROJ, NPROJ);
  for (int i = 0; i < 3; ++i)
    k_transT<<<dim3(32, 32), 256, 0, stream>>>(gat_W + (size_t)i * NPROJ * NPROJ,
                                               gwh + (size_t)i * NPROJ * NPROJ,
                                               NPROJ, NPROJ);
  k_transT<<<dim3(16, 32), 256, 0, stream>>>(pW1, pwh, NPROJ, 512);

  // ---- input f16 (scratch inside hb) + projection ----
  _Float16* inh = (_Float16*)hb;
  k_tof16<<<((N * NPROJ / 8) + 255) / 256, 256, 0, stream>>>(x_in, inh,
                                                             N * NPROJ / 8);
  const int MB = (N + 127) / 128;       // 79
  const int mpad8 = (MB + 7) / 8;       // 10
  const dim3 grid8(8 * mpad8 * 8);      // Nc=1024: lgn=3
  const dim3 grid4(4 * mpad8 * 8);      // Nc=512:  lgn=2
  gemm_mfma<0, 1><<<grid8, 256, 0, stream>>>(
      inh, pjh, proj_b, nullptr, xh, xl, nullptr, nullptr, nullptr, nullptr,
      N, NPROJ, 3, mpad8);

  // ---- 3 GAT layers (alpha fused into GEMM epilogue) ----
  for (int i = 0; i < 3; ++i) {
    hipMemsetAsync(asb, 0, (size_t)N * 4 * sizeof(float), stream);
    hipMemsetAsync(adb, 0, (size_t)N * 4 * sizeof(float), stream);
    gemm_mfma<0, 2><<<grid8, 256, 0, stream>>>(
        xh, gwh + (size_t)i * NPROJ * NPROJ,
        nullptr, nullptr, hf, nullptr,
        a_src + i * NPROJ, a_dst + i * NPROJ, asb, adb,
        N, NPROJ, 3, mpad8);
    k_aggregate_ln<<<N, 256, 0, stream>>>(hf, asb, adb, rowst, ccol,
                                          gat_b + i * NPROJ, gamma + i * NPROJ,
                                          beta + i * NPROJ, xh, xl);
  }

  // ---- attention pooling ----
  float* tb = hb;  // N x 512 f32
  gemm_mfma<1, 0><<<grid4, 256, 0, stream>>>(
      xh, pwh, pb1, tb, nullptr, nullptr, nullptr, nullptr, nullptr, nullptr,
      N, 512, 2, mpad8);
  k_scores<<<N, 64, 0, stream>>>(tb, pW2, pb2, scores, N);
  k_grange_init<<<1, 64, 0, stream>>>(gstart, gend, N);
  k_grange_mark<<<(N + 255) / 256, 256, 0, stream>>>(batch, gstart, gend, N);
  k_pool<<<NGRAPH, 256, 0, stream>>>(scores, xh, xl, gstart, gend, pooled);

  // ---- classifier ----
  k_cls1<<<dim3(2, NGRAPH), 256, 0, stream>>>(pooled, cW1, cb1, hid);
  k_cls2<<<dim3(14, NGRAPH), 64, 0, stream>>>(hid, cW2, cb2, out);
}

// Round 11
// 505.521 us; speedup vs baseline: 1.1784x; 1.1784x over previous
//
#include <hip/hip_runtime.h>
#include <hip/hip_bf16.h>
#include <hip/hip_fp16.h>
#include <math.h>

#define NPROJ 1024
#define NHEADS 4
#define NHID 256
#define NGRAPH 64

typedef _Float16 half8 __attribute__((ext_vector_type(8)));
typedef _Float16 half4v __attribute__((ext_vector_type(4)));
typedef float floatx4 __attribute__((ext_vector_type(4)));

#define GLD_LDS16(g, l)                                                        \
  __builtin_amdgcn_global_load_lds(                                            \
      (const __attribute__((address_space(1))) unsigned int*)(g),              \
      (__attribute__((address_space(3))) unsigned int*)(l), 16, 0, 0)

// ============================================================
// Single-product f16 MFMA GEMM:  C = A @ BT^T   (K fixed = 1024)
// A: M x 1024 f16 (hi of fp32).  B TRANSPOSED: Nc x 1024 f16 (hi of fp32).
// 128x128 tile, BK=64, 4 waves (2x2), wave 64x64, 16x16x32 MFMA.
// LDS = 2 x 16KB = 32KB -> 4 blocks/CU; grid 640 fits one residency round.
// Single-buffer overlap: frags->regs, barrier, STAGE(t+1) under MFMAs.
// XOR-swizzled LDS via pre-swizzled global source.
// XCD-chunked grid: each XCD owns mpad8 contiguous row-slabs, bx fastest.
// ============================================================
template<int ACT, int OUT>  // ACT: 0 none, 1 tanh; OUT: 0 f32, 1 split pair, 2 f16
__global__ __launch_bounds__(256, 4) void gemm_mfma(
    const _Float16* __restrict__ A, const _Float16* __restrict__ BT,
    const float* __restrict__ bias, float* __restrict__ Cf,
    _Float16* __restrict__ Ch, _Float16* __restrict__ Cl,
    int M, int Nc, int lgn, int mpad8)
{
  __shared__ __align__(16) _Float16 ldsA[128 * 64];
  __shared__ __align__(16) _Float16 ldsB[128 * 64];

  const int id  = blockIdx.x;
  const int xcd = id & 7;
  const int kk  = id >> 3;
  const int bx  = kk & ((1 << lgn) - 1);
  const int by  = xcd * mpad8 + (kk >> lgn);
  const int m0  = by * 128, n0 = bx * 128;
  if (m0 >= M) return;

  const int tid  = threadIdx.x;
  const int lane = tid & 63;
  const int wave = tid >> 6;
  const int wm = wave >> 1, wn = wave & 1;

  const int srow = tid >> 3;                              // + r*32
  const int kc8  = (((tid & 7) ^ ((tid >> 3) & 7)) << 3); // logical k elems
  const int wb16 = (tid & ~63) * 16;                      // wave-uniform base

  floatx4 acc[4][4] = {};

  const int l15 = lane & 15;
  const int swz = (l15 & 7) << 4;
  const int kbyte0 = (lane >> 4) * 16;

  auto STAGE = [&](int t) {
    const int k0 = t << 6;
#pragma unroll
    for (int r = 0; r < 4; ++r) {
      int rowA = m0 + r * 32 + srow;
      rowA = rowA < M ? rowA : (M - 1);
      GLD_LDS16(A + (size_t)rowA * 1024 + k0 + kc8,
                (char*)ldsA + r * 4096 + wb16);
      GLD_LDS16(BT + (size_t)(n0 + r * 32 + srow) * 1024 + k0 + kc8,
                (char*)ldsB + r * 4096 + wb16);
    }
  };

  STAGE(0);
  __syncthreads();

  for (int t = 0; t < 16; ++t) {
    const int koff0 = kbyte0 ^ swz;
    half8 a0[4], b0[4];
#pragma unroll
    for (int i = 0; i < 4; ++i)
      a0[i] = *(const half8*)((const char*)ldsA +
                              (wm * 64 + i * 16 + l15) * 128 + koff0);
#pragma unroll
    for (int j = 0; j < 4; ++j)
      b0[j] = *(const half8*)((const char*)ldsB +
                              (wn * 64 + j * 16 + l15) * 128 + koff0);
#pragma unroll
    for (int i = 0; i < 4; ++i)
#pragma unroll
      for (int j = 0; j < 4; ++j)
        acc[i][j] = __builtin_amdgcn_mfma_f32_16x16x32_f16(a0[i], b0[j],
                                                           acc[i][j], 0, 0, 0);

    const int koff1 = (64 + kbyte0) ^ swz;
    half8 a1[4], b1[4];
#pragma unroll
    for (int i = 0; i < 4; ++i)
      a1[i] = *(const half8*)((const char*)ldsA +
                              (wm * 64 + i * 16 + l15) * 128 + koff1);
#pragma unroll
    for (int j = 0; j < 4; ++j)
      b1[j] = *(const half8*)((const char*)ldsB +
                              (wn * 64 + j * 16 + l15) * 128 + koff1);
    __syncthreads();            // all LDS reads of tile t complete (regs held)
    if (t < 15) STAGE(t + 1);   // overwrite LDS under the MFMAs below

#pragma unroll
    for (int i = 0; i < 4; ++i)
#pragma unroll
      for (int j = 0; j < 4; ++j)
        acc[i][j] = __builtin_amdgcn_mfma_f32_16x16x32_f16(a1[i], b1[j],
                                                           acc[i][j], 0, 0, 0);

    if (t < 15) __syncthreads();  // vmcnt drain (mostly hidden by MFMAs)
  }

  // epilogue: C[row = (lane>>4)*4 + reg, col = lane&15] per 16x16 frag
  const int rbase = (lane >> 4) * 4;
#pragma unroll
  for (int j = 0; j < 4; ++j) {
    const int col = n0 + wn * 64 + j * 16 + l15;
    const float bv = bias ? bias[col] : 0.f;
#pragma unroll
    for (int i = 0; i < 4; ++i) {
      const int gm0 = m0 + wm * 64 + i * 16 + rbase;
#pragma unroll
      for (int r = 0; r < 4; ++r) {
        const int gm = gm0 + r;
        if (gm >= M) continue;
        float v = acc[i][j][r] + bv;
        if (ACT == 1) v = tanhf(v);
        if (OUT == 1) {
          _Float16 hh = (_Float16)v;
          Ch[(size_t)gm * Nc + col] = hh;
          Cl[(size_t)gm * Nc + col] = (_Float16)(v - (float)hh);
        } else if (OUT == 2) {
          Ch[(size_t)gm * Nc + col] = (_Float16)v;
        } else {
          Cf[(size_t)gm * Nc + col] = v;
        }
      }
    }
  }
}

// ============================================================
// converters
// ============================================================
__global__ void k_tof16(const float* __restrict__ in, _Float16* __restrict__ h,
                        int L8) {
  int i = blockIdx.x * 256 + threadIdx.x;
  if (i >= L8) return;
  const float4* p = (const float4*)(in + (size_t)i * 8);
  float4 v0 = p[0], v1 = p[1];
  float vv[8] = {v0.x, v0.y, v0.z, v0.w, v1.x, v1.y, v1.z, v1.w};
  half8 hv;
#pragma unroll
  for (int j = 0; j < 8; ++j) hv[j] = (_Float16)vv[j];
  *(half8*)(h + (size_t)i * 8) = hv;
}

// W (K x Nc) fp32 -> transposed (Nc x K) f16
__global__ __launch_bounds__(256) void k_transT(const float* __restrict__ in,
                                                _Float16* __restrict__ hT,
                                                int K, int Nc) {
  __shared__ float t[32][33];
  const int tx = threadIdx.x & 31, ty = threadIdx.x >> 5;
  const int c0 = blockIdx.x * 32, k0 = blockIdx.y * 32;
#pragma unroll
  for (int r = 0; r < 4; ++r)
    t[ty + 8 * r][tx] = in[(size_t)(k0 + ty + 8 * r) * Nc + c0 + tx];
  __syncthreads();
#pragma unroll
  for (int r = 0; r < 4; ++r) {
    float v = t[tx][ty + 8 * r];
    int oc = c0 + ty + 8 * r;
    hT[(size_t)oc * K + k0 + tx] = (_Float16)v;
  }
}

// ============================================================
// CSR-by-dst construction (recomputed every call; no caching)
// ============================================================
__global__ void k_init_counts(int* cnt, int n) {
  int i = blockIdx.x * 256 + threadIdx.x;
  if (i < n) cnt[i] = 1;  // self-loop pre-counted
}

__global__ void k_count(const int* __restrict__ dst, int* cnt, int e) {
  int i = blockIdx.x * 256 + threadIdx.x;
  if (i < e) atomicAdd(&cnt[dst[i]], 1);
}

__global__ __launch_bounds__(1024) void k_scan(const int* __restrict__ cnt,
                                               int* __restrict__ rowstart,
                                               int* __restrict__ cursor, int n) {
  __shared__ int buf[1024];
  __shared__ int carry;
  int t = threadIdx.x;
  if (t == 0) carry = 0;
  __syncthreads();
  for (int base = 0; base < n; base += 1024) {
    int x = (base + t < n) ? cnt[base + t] : 0;
    buf[t] = x;
    __syncthreads();
    for (int off = 1; off < 1024; off <<= 1) {
      int v = (t >= off) ? buf[t - off] : 0;
      __syncthreads();
      buf[t] += v;
      __syncthreads();
    }
    int c0 = carry;
    int excl = buf[t] - x + c0;
    if (base + t < n) { rowstart[base + t] = excl; cursor[base + t] = excl; }
    __syncthreads();
    if (t == 0) carry = c0 + buf[1023];
    __syncthreads();
  }
  if (t == 0) rowstart[n] = carry;
}

__global__ void k_fill(const int* __restrict__ src, const int* __restrict__ dst,
                       int* cursor, int* __restrict__ col, int e) {
  int i = blockIdx.x * 256 + threadIdx.x;
  if (i < e) {
    int p = atomicAdd(&cursor[dst[i]], 1);
    col[p] = src[i];
  }
}

__global__ void k_fill_self(int* cursor, int* __restrict__ col, int n) {
  int i = blockIdx.x * 256 + threadIdx.x;
  if (i < n) {
    int p = atomicAdd(&cursor[i], 1);
    col[p] = i;
  }
}

// ============================================================
// per-node attention logits (f16 h): one wave per head
// ============================================================
__global__ __launch_bounds__(256) void k_alpha(
    const _Float16* __restrict__ h, const float* __restrict__ a_src,
    const float* __restrict__ a_dst, float* __restrict__ as_out,
    float* __restrict__ ad_out) {
  int n = blockIdx.x, t = threadIdx.x;
  const int wv = t >> 6, ln = t & 63;     // wave = head
  const int cb = wv * 256 + 4 * ln;
  half4v v = *(const half4v*)(h + (size_t)n * NPROJ + cb);
  float4 s4 = *(const float4*)(a_src + cb);
  float4 d4 = *(const float4*)(a_dst + cb);
  float vv[4] = {(float)v[0], (float)v[1], (float)v[2], (float)v[3]};
  float ss = vv[0] * s4.x + vv[1] * s4.y + vv[2] * s4.z + vv[3] * s4.w;
  float sd = vv[0] * d4.x + vv[1] * d4.y + vv[2] * d4.z + vv[3] * d4.w;
#pragma unroll
  for (int off = 32; off > 0; off >>= 1) {
    ss += __shfl_down(ss, off);
    sd += __shfl_down(sd, off);
  }
  if (ln == 0) {
    as_out[n * 4 + wv] = ss;
    ad_out[n * 4 + wv] = sd;
  }
}

// ============================================================
// fused segment-softmax + aggregation + bias/ELU/residual/LayerNorm
// r8 form (wave-per-head, in-wave shfl softmax, 1 barrier) with a
// MILD unroll-4 gather: 4 loads in flight per waitcnt, ~36 VGPR
// (r9's unroll-16 cost 56 VGPR and halved occupancy -- reverted).
// ============================================================
__device__ __forceinline__ float lrelu02(float x) {
  return x > 0.f ? x : 0.2f * x;
}

__global__ __launch_bounds__(256) void k_aggregate_ln(
    const _Float16* __restrict__ h, const float* __restrict__ as_,
    const float* __restrict__ ad_, const int* __restrict__ rowstart,
    const int* __restrict__ col, const float* __restrict__ bias,
    const float* __restrict__ gamma, const float* __restrict__ beta,
    _Float16* __restrict__ xh, _Float16* __restrict__ xl) {
  __shared__ float sred[8];

  const int n = blockIdx.x, t = threadIdx.x;
  const int wv = t >> 6, l = t & 63;
  const int rs = rowstart[n], re = rowstart[n + 1];
  const float adn = ad_[n * 4 + wv];

  // pass 1: per-head max (in-wave)
  float mx = -1e30f;
  for (int e = rs + l; e < re; e += 64)
    mx = fmaxf(mx, lrelu02(as_[(size_t)col[e] * 4 + wv] + adn));
#pragma unroll
  for (int off = 32; off > 0; off >>= 1)
    mx = fmaxf(mx, __shfl_xor(mx, off));

  // pass 2: sum of exp (in-wave)
  float sm = 0.f;
  for (int e = rs + l; e < re; e += 64)
    sm += expf(lrelu02(as_[(size_t)col[e] * 4 + wv] + adn) - mx);
#pragma unroll
  for (int off = 32; off > 0; off >>= 1)
    sm += __shfl_xor(sm, off);
  const float Sinv = 1.f / (sm + 1e-16f);

  // pass 3: gather; lane owns cols wv*256 + 4l .. +3 ; unroll-4 MLP
  const int cb = wv * 256 + 4 * l;
  float acc[4] = {0.f, 0.f, 0.f, 0.f};
  for (int c0 = rs; c0 < re; c0 += 64) {
    const int idx = c0 + l;
    float w_l = 0.f;
    int s_l = 0;
    if (idx < re) {
      s_l = col[idx];
      w_l = expf(lrelu02(as_[(size_t)s_l * 4 + wv] + adn) - mx) * Sinv;
    }
    const int cnt = min(64, re - c0);
    int e = 0;
    for (; e + 3 < cnt; e += 4) {
      float w0 = __shfl(w_l, e + 0), w1 = __shfl(w_l, e + 1);
      float w2 = __shfl(w_l, e + 2), w3 = __shfl(w_l, e + 3);
      int s0 = __shfl(s_l, e + 0), s1 = __shfl(s_l, e + 1);
      int s2 = __shfl(s_l, e + 2), s3 = __shfl(s_l, e + 3);
      half4v h0 = *(const half4v*)(h + (size_t)s0 * NPROJ + cb);
      half4v h1 = *(const half4v*)(h + (size_t)s1 * NPROJ + cb);
      half4v h2 = *(const half4v*)(h + (size_t)s2 * NPROJ + cb);
      half4v h3 = *(const half4v*)(h + (size_t)s3 * NPROJ + cb);
#pragma unroll
      for (int j = 0; j < 4; ++j) {
        acc[j] = fmaf(w0, (float)h0[j], acc[j]);
        acc[j] = fmaf(w1, (float)h1[j], acc[j]);
        acc[j] = fmaf(w2, (float)h2[j], acc[j]);
        acc[j] = fmaf(w3, (float)h3[j], acc[j]);
      }
    }
    for (; e < cnt; ++e) {
      const float w = __shfl(w_l, e);
      const int s = __shfl(s_l, e);
      half4v hv = *(const half4v*)(h + (size_t)s * NPROJ + cb);
      acc[0] = fmaf(w, (float)hv[0], acc[0]);
      acc[1] = fmaf(w, (float)hv[1], acc[1]);
      acc[2] = fmaf(w, (float)hv[2], acc[2]);
      acc[3] = fmaf(w, (float)hv[3], acc[3]);
    }
  }

  // epilogue: bias, ELU, residual; LayerNorm stats
  const size_t base = (size_t)n * NPROJ + cb;
  float4 b4 = *(const float4*)(bias + cb);
  float bb[4] = {b4.x, b4.y, b4.z, b4.w};
  half4v xhv = *(const half4v*)(xh + base);
  half4v xlv = *(const half4v*)(xl + base);
  float v[4];
  float sum = 0.f, sumsq = 0.f;
#pragma unroll
  for (int j = 0; j < 4; ++j) {
    float u = acc[j] + bb[j];
    u = u > 0.f ? u : expm1f(u);
    u += (float)xhv[j] + (float)xlv[j];
    v[j] = u;
    sum += u;
    sumsq += u * u;
  }
#pragma unroll
  for (int off = 32; off > 0; off >>= 1) {
    sum += __shfl_xor(sum, off);
    sumsq += __shfl_xor(sumsq, off);
  }
  if (l == 0) {
    sred[wv] = sum;
    sred[4 + wv] = sumsq;
  }
  __syncthreads();
  const float tsum = sred[0] + sred[1] + sred[2] + sred[3];
  const float tssq = sred[4] + sred[5] + sred[6] + sred[7];
  const float mu = tsum * (1.f / 1024.f);
  const float var = tssq * (1.f / 1024.f) - mu * mu;
  const float rstd = rsqrtf(var + 1e-5f);

  float4 g4 = *(const float4*)(gamma + cb);
  float4 e4 = *(const float4*)(beta + cb);
  float gg[4] = {g4.x, g4.y, g4.z, g4.w};
  float ee[4] = {e4.x, e4.y, e4.z, e4.w};
  half4v oh, ol;
#pragma unroll
  for (int j = 0; j < 4; ++j) {
    float y = (v[j] - mu) * rstd * gg[j] + ee[j];
    _Float16 hh = (_Float16)y;
    oh[j] = hh;
    ol[j] = (_Float16)(y - (float)hh);
  }
  *(half4v*)(xh + base) = oh;
  *(half4v*)(xl + base) = ol;
}

// ============================================================
// pooling + classifier
// ============================================================
__global__ void k_scores(const float* __restrict__ tb,
                         const float* __restrict__ W2,
                         const float* __restrict__ b2,
                         float* __restrict__ scores, int N) {
  int n = blockIdx.x, lane = threadIdx.x;
  float s = 0.f;
  for (int k = lane; k < 512; k += 64) s = fmaf(tb[(size_t)n * 512 + k], W2[k], s);
  for (int off = 32; off > 0; off >>= 1) s += __shfl_down(s, off);
  if (lane == 0) scores[n] = s + b2[0];
}

__global__ void k_grange_init(int* gstart, int* gend, int N) {
  int g = threadIdx.x;
  if (g < NGRAPH) { gstart[g] = N; gend[g] = 0; }
}

__global__ void k_grange_mark(const int* __restrict__ batch, int* gstart,
                              int* gend, int N) {
  int n = blockIdx.x * 256 + threadIdx.x;
  if (n >= N) return;
  int b = batch[n];
  if (n == 0 || batch[n - 1] != b) gstart[b] = n;
  if (n == N - 1 || batch[n + 1] != b) gend[b] = n + 1;
}

__global__ __launch_bounds__(256) void k_pool(
    const float* __restrict__ scores, const _Float16* __restrict__ xh,
    const _Float16* __restrict__ xl, const int* __restrict__ gstart,
    const int* __restrict__ gend, float* __restrict__ pooled) {
  __shared__ float red[256];
  __shared__ float wt[256];
  __shared__ float m_s, s_s;
  int g = blockIdx.x, t = threadIdx.x;
  int rs = gstart[g], re = gend[g];

  float mx = -1e30f;
  for (int i = rs + t; i < re; i += 256) mx = fmaxf(mx, scores[i]);
  red[t] = mx;
  __syncthreads();
  for (int s = 128; s > 0; s >>= 1) {
    if (t < s) red[t] = fmaxf(red[t], red[t + s]);
    __syncthreads();
  }
  if (t == 0) m_s = red[0];
  __syncthreads();
  float m = m_s;

  float sm = 0.f;
  for (int i = rs + t; i < re; i += 256) sm += expf(scores[i] - m);
  red[t] = sm;
  __syncthreads();
  for (int s = 128; s > 0; s >>= 1) {
    if (t < s) red[t] += red[t + s];
    __syncthreads();
  }
  if (t == 0) s_s = red[0] + 1e-16f;
  __syncthreads();
  float sden = s_s;

  float acc[4] = {0.f, 0.f, 0.f, 0.f};
  for (int c0 = rs; c0 < re; c0 += 256) {
    int cnt = min(256, re - c0);
    if (t < cnt) wt[t] = expf(scores[c0 + t] - m) / sden;
    __syncthreads();
    for (int e = 0; e < cnt; ++e) {
      float w = wt[e];
      size_t base = (size_t)(c0 + e) * NPROJ + 4 * t;
      half4v hv = *(const half4v*)(xh + base);
      half4v lv = *(const half4v*)(xl + base);
#pragma unroll
      for (int j = 0; j < 4; ++j)
        acc[j] = fmaf(w, (float)hv[j] + (float)lv[j], acc[j]);
    }
    __syncthreads();
  }
#pragma unroll
  for (int j = 0; j < 4; ++j) pooled[(size_t)g * NPROJ + 4 * t + j] = acc[j];
}

__global__ __launch_bounds__(256) void k_cls1(const float* __restrict__ pooled,
                                              const float* __restrict__ W1,
                                              const float* __restrict__ b1,
                                              float* __restrict__ hid) {
  __shared__ float p[1024];
  int g = blockIdx.y;
  int colc = blockIdx.x * 256 + threadIdx.x;
  for (int k = threadIdx.x; k < 1024; k += 256) p[k] = pooled[(size_t)g * 1024 + k];
  __syncthreads();
  float s = 0.f;
  for (int k = 0; k < 1024; ++k) s = fmaf(p[k], W1[(size_t)k * 512 + colc], s);
  s += b1[colc];
  s = 0.5f * s * (1.f + erff(s * 0.70710678118654752f));
  hid[(size_t)g * 512 + colc] = s;
}

__global__ void k_cls2(const float* __restrict__ hid,
                       const float* __restrict__ W2,
                       const float* __restrict__ b2, float* __restrict__ out) {
  int o = blockIdx.x, g = blockIdx.y, lane = threadIdx.x;
  float s = 0.f;
  for (int k = lane; k < 512; k += 64) s = fmaf(hid[(size_t)g * 512 + k], W2[k * 14 + o], s);
  for (int off = 32; off > 0; off >>= 1) s += __shfl_down(s, off);
  if (lane == 0) out[g * 14 + o] = s + b2[o];
}

// ============================================================
extern "C" void kernel_launch(void* const* d_in, const int* in_sizes, int n_in,
                              void* d_out, int out_size, void* d_ws, size_t ws_size,
                              hipStream_t stream) {
  const float* x_in   = (const float*)d_in[0];
  const int*   eidx   = (const int*)d_in[1];
  const int*   batch  = (const int*)d_in[2];
  const float* proj_W = (const float*)d_in[3];
  const float* proj_b = (const float*)d_in[4];
  const float* gat_W  = (const float*)d_in[5];
  const float* a_src  = (const float*)d_in[6];
  const float* a_dst  = (const float*)d_in[7];
  const float* gat_b  = (const float*)d_in[8];
  const float* gamma  = (const float*)d_in[9];
  const float* beta   = (const float*)d_in[10];
  const float* pW1    = (const float*)d_in[11];
  const float* pb1    = (const float*)d_in[12];
  const float* pW2    = (const float*)d_in[13];
  const float* pb2    = (const float*)d_in[14];
  const float* cW1    = (const float*)d_in[15];
  const float* cb1    = (const float*)d_in[16];
  const float* cW2    = (const float*)d_in[17];
  const float* cb2    = (const float*)d_in[18];
  float* out = (float*)d_out;

  const int N = in_sizes[0] / NPROJ;  // 10000
  const int E = in_sizes[1] / 2;      // 160000
  const int Etot = E + N;

  char* ws = (char*)d_ws;
  size_t off = 0;
  auto alloc = [&](size_t bytes) -> void* {
    void* p = ws + off;
    off = (off + bytes + 255) & ~(size_t)255;
    return p;
  };
  _Float16* xh   = (_Float16*)alloc((size_t)N * NPROJ * 2);
  _Float16* xl   = (_Float16*)alloc((size_t)N * NPROJ * 2);
  _Float16* hf   = (_Float16*)alloc((size_t)N * NPROJ * 2);   // f16 h
  float*    hb   = (float*)alloc((size_t)N * NPROJ * 4);      // in-f16 / tb
  _Float16* pjh  = (_Float16*)alloc((size_t)NPROJ * NPROJ * 2);
  _Float16* gwh  = (_Float16*)alloc((size_t)3 * NPROJ * NPROJ * 2);
  _Float16* pwh  = (_Float16*)alloc((size_t)512 * NPROJ * 2);
  float* asb     = (float*)alloc((size_t)N * 4 * 4);
  float* adb     = (float*)alloc((size_t)N * 4 * 4);
  int*   cnt     = (int*)alloc((size_t)N * 4);
  int*   rowst   = (int*)alloc((size_t)(N + 1) * 4);
  int*   cursor  = (int*)alloc((size_t)N * 4);
  int*   ccol    = (int*)alloc((size_t)Etot * 4);
  float* scores  = (float*)alloc((size_t)N * 4);
  int*   gstart  = (int*)alloc(NGRAPH * 4);
  int*   gend    = (int*)alloc(NGRAPH * 4);
  float* pooled  = (float*)alloc((size_t)NGRAPH * NPROJ * 4);
  float* hid     = (float*)alloc((size_t)NGRAPH * 512 * 4);

  const int* esrc = eidx;
  const int* edst = eidx + E;

  // ---- CSR by dst ----
  k_init_counts<<<(N + 255) / 256, 256, 0, stream>>>(cnt, N);
  k_count<<<(E + 255) / 256, 256, 0, stream>>>(edst, cnt, E);
  k_scan<<<1, 1024, 0, stream>>>(cnt, rowst, cursor, N);
  k_fill<<<(E + 255) / 256, 256, 0, stream>>>(esrc, edst, cursor, ccol, E);
  k_fill_self<<<(N + 255) / 256, 256, 0, stream>>>(cursor, ccol, N);

  // ---- weight transposes (f16 hi) ----
  k_transT<<<dim3(32, 32), 256, 0, stream>>>(proj_W, pjh, NPROJ, NPROJ);
  for (int i = 0; i < 3; ++i)
    k_transT<<<dim3(32, 32), 256, 0, stream>>>(gat_W + (size_t)i * NPROJ * NPROJ,
                                               gwh + (size_t)i * NPROJ * NPROJ,
                                               NPROJ, NPROJ);
  k_transT<<<dim3(16, 32), 256, 0, stream>>>(pW1, pwh, NPROJ, 512);

  // ---- input f16 (scratch inside hb) + projection ----
  _Float16* inh = (_Float16*)hb;
  k_tof16<<<((N * NPROJ / 8) + 255) / 256, 256, 0, stream>>>(x_in, inh,
                                                             N * NPROJ / 8);
  const int MB = (N + 127) / 128;       // 79
  const int mpad8 = (MB + 7) / 8;       // 10
  const dim3 grid8(8 * mpad8 * 8);      // Nc=1024: lgn=3
  const dim3 grid4(4 * mpad8 * 8);      // Nc=512:  lgn=2
  gemm_mfma<0, 1><<<grid8, 256, 0, stream>>>(
      inh, pjh, proj_b, nullptr, xh, xl, N, NPROJ, 3, mpad8);

  // ---- 3 GAT layers ----
  for (int i = 0; i < 3; ++i) {
    gemm_mfma<0, 2><<<grid8, 256, 0, stream>>>(
        xh, gwh + (size_t)i * NPROJ * NPROJ,
        nullptr, nullptr, hf, nullptr, N, NPROJ, 3, mpad8);
    k_alpha<<<N, 256, 0, stream>>>(hf, a_src + i * NPROJ, a_dst + i * NPROJ, asb, adb);
    k_aggregate_ln<<<N, 256, 0, stream>>>(hf, asb, adb, rowst, ccol,
                                          gat_b + i * NPROJ, gamma + i * NPROJ,
                                          beta + i * NPROJ, xh, xl);
  }

  // ---- attention pooling ----
  float* tb = hb;  // N x 512 f32
  gemm_mfma<1, 0><<<grid4, 256, 0, stream>>>(
      xh, pwh, pb1, tb, nullptr, nullptr, N, 512, 2, mpad8);
  k_scores<<<N, 64, 0, stream>>>(tb, pW2, pb2, scores, N);
  k_grange_init<<<1, 64, 0, stream>>>(gstart, gend, N);
  k_grange_mark<<<(N + 255) / 256, 256, 0, stream>>>(batch, gstart, gend, N);
  k_pool<<<NGRAPH, 256, 0, stream>>>(scores, xh, xl, gstart, gend, pooled);

  // ---- classifier ----
  k_cls1<<<dim3(2, NGRAPH), 256, 0, stream>>>(pooled, cW1, cb1, hid);
  k_cls2<<<dim3(14, NGRAPH), 64, 0, stream>>>(hid, cW2, cb2, out);
}

// Round 12
// 483.976 us; speedup vs baseline: 1.2309x; 1.0445x over previous
//
#include <hip/hip_runtime.h>
#include <hip/hip_bf16.h>
#include <hip/hip_fp16.h>
#include <math.h>

#define NPROJ 1024
#define NHEADS 4
#define NHID 256
#define NGRAPH 64

typedef _Float16 half8 __attribute__((ext_vector_type(8)));
typedef _Float16 half4v __attribute__((ext_vector_type(4)));
typedef float floatx4 __attribute__((ext_vector_type(4)));

#define GLD_LDS16(g, l)                                                        \
  __builtin_amdgcn_global_load_lds(                                            \
      (const __attribute__((address_space(1))) unsigned int*)(g),              \
      (__attribute__((address_space(3))) unsigned int*)(l), 16, 0, 0)

// ============================================================
// Single-product f16 MFMA GEMM:  C = A @ BT^T   (K fixed = 1024)
// A: M x 1024 f16 (hi of fp32).  B TRANSPOSED: Nc x 1024 f16 (hi of fp32).
// 128x128 tile, BK=64, 4 waves (2x2), wave 64x64, 16x16x32 MFMA.
// LDS = 2 x 16KB = 32KB -> 4 blocks/CU; grid 640 fits one residency round.
// Single-buffer overlap: frags->regs, barrier, STAGE(t+1) under MFMAs.
// XOR-swizzled LDS via pre-swizzled global source.
// XCD-chunked grid: each XCD owns mpad8 contiguous row-slabs, bx fastest.
// ============================================================
template<int ACT, int OUT>  // ACT: 0 none, 1 tanh; OUT: 0 f32, 1 split pair, 2 f16
__global__ __launch_bounds__(256, 4) void gemm_mfma(
    const _Float16* __restrict__ A, const _Float16* __restrict__ BT,
    const float* __restrict__ bias, float* __restrict__ Cf,
    _Float16* __restrict__ Ch, _Float16* __restrict__ Cl,
    int M, int Nc, int lgn, int mpad8)
{
  __shared__ __align__(16) _Float16 ldsA[128 * 64];
  __shared__ __align__(16) _Float16 ldsB[128 * 64];

  const int id  = blockIdx.x;
  const int xcd = id & 7;
  const int kk  = id >> 3;
  const int bx  = kk & ((1 << lgn) - 1);
  const int by  = xcd * mpad8 + (kk >> lgn);
  const int m0  = by * 128, n0 = bx * 128;
  if (m0 >= M) return;

  const int tid  = threadIdx.x;
  const int lane = tid & 63;
  const int wave = tid >> 6;
  const int wm = wave >> 1, wn = wave & 1;

  const int srow = tid >> 3;                              // + r*32
  const int kc8  = (((tid & 7) ^ ((tid >> 3) & 7)) << 3); // logical k elems
  const int wb16 = (tid & ~63) * 16;                      // wave-uniform base

  floatx4 acc[4][4] = {};

  const int l15 = lane & 15;
  const int swz = (l15 & 7) << 4;
  const int kbyte0 = (lane >> 4) * 16;

  auto STAGE = [&](int t) {
    const int k0 = t << 6;
#pragma unroll
    for (int r = 0; r < 4; ++r) {
      int rowA = m0 + r * 32 + srow;
      rowA = rowA < M ? rowA : (M - 1);
      GLD_LDS16(A + (size_t)rowA * 1024 + k0 + kc8,
                (char*)ldsA + r * 4096 + wb16);
      GLD_LDS16(BT + (size_t)(n0 + r * 32 + srow) * 1024 + k0 + kc8,
                (char*)ldsB + r * 4096 + wb16);
    }
  };

  STAGE(0);
  __syncthreads();

  for (int t = 0; t < 16; ++t) {
    const int koff0 = kbyte0 ^ swz;
    half8 a0[4], b0[4];
#pragma unroll
    for (int i = 0; i < 4; ++i)
      a0[i] = *(const half8*)((const char*)ldsA +
                              (wm * 64 + i * 16 + l15) * 128 + koff0);
#pragma unroll
    for (int j = 0; j < 4; ++j)
      b0[j] = *(const half8*)((const char*)ldsB +
                              (wn * 64 + j * 16 + l15) * 128 + koff0);
#pragma unroll
    for (int i = 0; i < 4; ++i)
#pragma unroll
      for (int j = 0; j < 4; ++j)
        acc[i][j] = __builtin_amdgcn_mfma_f32_16x16x32_f16(a0[i], b0[j],
                                                           acc[i][j], 0, 0, 0);

    const int koff1 = (64 + kbyte0) ^ swz;
    half8 a1[4], b1[4];
#pragma unroll
    for (int i = 0; i < 4; ++i)
      a1[i] = *(const half8*)((const char*)ldsA +
                              (wm * 64 + i * 16 + l15) * 128 + koff1);
#pragma unroll
    for (int j = 0; j < 4; ++j)
      b1[j] = *(const half8*)((const char*)ldsB +
                              (wn * 64 + j * 16 + l15) * 128 + koff1);
    __syncthreads();            // all LDS reads of tile t complete (regs held)
    if (t < 15) STAGE(t + 1);   // overwrite LDS under the MFMAs below

#pragma unroll
    for (int i = 0; i < 4; ++i)
#pragma unroll
      for (int j = 0; j < 4; ++j)
        acc[i][j] = __builtin_amdgcn_mfma_f32_16x16x32_f16(a1[i], b1[j],
                                                           acc[i][j], 0, 0, 0);

    if (t < 15) __syncthreads();  // vmcnt drain (mostly hidden by MFMAs)
  }

  // epilogue: C[row = (lane>>4)*4 + reg, col = lane&15] per 16x16 frag
  const int rbase = (lane >> 4) * 4;
#pragma unroll
  for (int j = 0; j < 4; ++j) {
    const int col = n0 + wn * 64 + j * 16 + l15;
    const float bv = bias ? bias[col] : 0.f;
#pragma unroll
    for (int i = 0; i < 4; ++i) {
      const int gm0 = m0 + wm * 64 + i * 16 + rbase;
#pragma unroll
      for (int r = 0; r < 4; ++r) {
        const int gm = gm0 + r;
        if (gm >= M) continue;
        float v = acc[i][j][r] + bv;
        if (ACT == 1) v = tanhf(v);
        if (OUT == 1) {
          _Float16 hh = (_Float16)v;
          Ch[(size_t)gm * Nc + col] = hh;
          Cl[(size_t)gm * Nc + col] = (_Float16)(v - (float)hh);
        } else if (OUT == 2) {
          Ch[(size_t)gm * Nc + col] = (_Float16)v;
        } else {
          Cf[(size_t)gm * Nc + col] = v;
        }
      }
    }
  }
}

// ============================================================
// converters
// ============================================================
__global__ void k_tof16(const float* __restrict__ in, _Float16* __restrict__ h,
                        int L8) {
  int i = blockIdx.x * 256 + threadIdx.x;
  if (i >= L8) return;
  const float4* p = (const float4*)(in + (size_t)i * 8);
  float4 v0 = p[0], v1 = p[1];
  float vv[8] = {v0.x, v0.y, v0.z, v0.w, v1.x, v1.y, v1.z, v1.w};
  half8 hv;
#pragma unroll
  for (int j = 0; j < 8; ++j) hv[j] = (_Float16)vv[j];
  *(half8*)(h + (size_t)i * 8) = hv;
}

// W (K x Nc) fp32 -> transposed (Nc x K) f16
__global__ __launch_bounds__(256) void k_transT(const float* __restrict__ in,
                                                _Float16* __restrict__ hT,
                                                int K, int Nc) {
  __shared__ float t[32][33];
  const int tx = threadIdx.x & 31, ty = threadIdx.x >> 5;
  const int c0 = blockIdx.x * 32, k0 = blockIdx.y * 32;
#pragma unroll
  for (int r = 0; r < 4; ++r)
    t[ty + 8 * r][tx] = in[(size_t)(k0 + ty + 8 * r) * Nc + c0 + tx];
  __syncthreads();
#pragma unroll
  for (int r = 0; r < 4; ++r) {
    float v = t[tx][ty + 8 * r];
    int oc = c0 + ty + 8 * r;
    hT[(size_t)oc * K + k0 + tx] = (_Float16)v;
  }
}

// ============================================================
// CSR-by-dst construction (recomputed every call; no caching)
// 3-level scan replaces the old single-block 200-barrier k_scan.
// ============================================================
__global__ void k_init_counts(int* cnt, int n) {
  int i = blockIdx.x * 256 + threadIdx.x;
  if (i < n) cnt[i] = 1;  // self-loop pre-counted
}

__global__ void k_count(const int* __restrict__ dst, int* cnt, int e) {
  int i = blockIdx.x * 256 + threadIdx.x;
  if (i < e) atomicAdd(&cnt[dst[i]], 1);
}

// level 1: per-256-block inclusive->exclusive scan (in place) + block sums
__global__ __launch_bounds__(256) void k_scan1(int* __restrict__ cnt,
                                               int* __restrict__ bsum, int n) {
  __shared__ int wsum[4];
  const int b = blockIdx.x, t = threadIdx.x, i = b * 256 + t;
  const int x = (i < n) ? cnt[i] : 0;
  int v = x;
#pragma unroll
  for (int off = 1; off < 64; off <<= 1) {
    int u = __shfl_up(v, off);
    if ((t & 63) >= off) v += u;
  }
  if ((t & 63) == 63) wsum[t >> 6] = v;
  __syncthreads();
  int wo = 0;
#pragma unroll
  for (int w = 0; w < 4; ++w) wo += (w < (t >> 6)) ? wsum[w] : 0;
  const int incl = v + wo;
  if (i < n) cnt[i] = incl - x;  // exclusive-within-block, in place
  if (t == 255) bsum[b] = incl;
}

// level 2: single-wave exclusive scan of block sums (nb <= 64)
__global__ void k_scan2(int* __restrict__ bsum, int nb) {
  const int t = threadIdx.x;
  const int x = (t < nb) ? bsum[t] : 0;
  int v = x;
#pragma unroll
  for (int off = 1; off < 64; off <<= 1) {
    int u = __shfl_up(v, off);
    if (t >= off) v += u;
  }
  if (t < nb) bsum[t] = v - x;  // exclusive, in place
}

// level 3: add block offsets, emit rowstart + cursor
__global__ void k_scan3(const int* __restrict__ cnt, const int* __restrict__ bsum,
                        int* __restrict__ rowstart, int* __restrict__ cursor,
                        int n, int etot) {
  const int i = blockIdx.x * 256 + threadIdx.x;
  if (i < n) {
    const int v = cnt[i] + bsum[i >> 8];
    rowstart[i] = v;
    cursor[i] = v;
  }
  if (i == 0) rowstart[n] = etot;
}

__global__ void k_fill(const int* __restrict__ src, const int* __restrict__ dst,
                       int* cursor, int* __restrict__ col, int e) {
  int i = blockIdx.x * 256 + threadIdx.x;
  if (i < e) {
    int p = atomicAdd(&cursor[dst[i]], 1);
    col[p] = src[i];
  }
}

__global__ void k_fill_self(int* cursor, int* __restrict__ col, int n) {
  int i = blockIdx.x * 256 + threadIdx.x;
  if (i < n) {
    int p = atomicAdd(&cursor[i], 1);
    col[p] = i;
  }
}

// ============================================================
// per-node attention logits (f16 h): half8 loads, 2 heads/wave,
// 2 nodes per 256-thread block
// ============================================================
__global__ __launch_bounds__(256) void k_alpha(
    const _Float16* __restrict__ h, const float* __restrict__ a_src,
    const float* __restrict__ a_dst, float* __restrict__ as_out,
    float* __restrict__ ad_out, int N) {
  const int t = threadIdx.x;
  const int w = t >> 6, l = t & 63;
  const int node = blockIdx.x * 2 + (w >> 1);
  if (node >= N) return;
  const int head = (w & 1) * 2 + (l >> 5);
  const int cb = head * 256 + (l & 31) * 8;
  half8 v = *(const half8*)(h + (size_t)node * NPROJ + cb);
  float4 s0 = *(const float4*)(a_src + cb);
  float4 s1 = *(const float4*)(a_src + cb + 4);
  float4 d0 = *(const float4*)(a_dst + cb);
  float4 d1 = *(const float4*)(a_dst + cb + 4);
  float sv[8] = {s0.x, s0.y, s0.z, s0.w, s1.x, s1.y, s1.z, s1.w};
  float dv[8] = {d0.x, d0.y, d0.z, d0.w, d1.x, d1.y, d1.z, d1.w};
  float ss = 0.f, sd = 0.f;
#pragma unroll
  for (int j = 0; j < 8; ++j) {
    float f = (float)v[j];
    ss = fmaf(f, sv[j], ss);
    sd = fmaf(f, dv[j], sd);
  }
#pragma unroll
  for (int off = 1; off <= 16; off <<= 1) {
    ss += __shfl_xor(ss, off);
    sd += __shfl_xor(sd, off);
  }
  if ((l & 31) == 0) {
    as_out[node * 4 + head] = ss;
    ad_out[node * 4 + head] = sd;
  }
}

// ============================================================
// fused segment-softmax + aggregation + bias/ELU/residual/LayerNorm
// r8 form (wave-per-head, in-wave shfl softmax, 1 barrier) with
// unroll-6 gather: 6 loads in flight per waitcnt (~40 VGPR --
// unroll-16 at 56 VGPR halved occupancy in r9, unroll-4=28 was fine).
// ============================================================
__device__ __forceinline__ float lrelu02(float x) {
  return x > 0.f ? x : 0.2f * x;
}

__global__ __launch_bounds__(256) void k_aggregate_ln(
    const _Float16* __restrict__ h, const float* __restrict__ as_,
    const float* __restrict__ ad_, const int* __restrict__ rowstart,
    const int* __restrict__ col, const float* __restrict__ bias,
    const float* __restrict__ gamma, const float* __restrict__ beta,
    _Float16* __restrict__ xh, _Float16* __restrict__ xl) {
  __shared__ float sred[8];

  const int n = blockIdx.x, t = threadIdx.x;
  const int wv = t >> 6, l = t & 63;
  const int rs = rowstart[n], re = rowstart[n + 1];
  const float adn = ad_[n * 4 + wv];

  // pass 1: per-head max (in-wave)
  float mx = -1e30f;
  for (int e = rs + l; e < re; e += 64)
    mx = fmaxf(mx, lrelu02(as_[(size_t)col[e] * 4 + wv] + adn));
#pragma unroll
  for (int off = 32; off > 0; off >>= 1)
    mx = fmaxf(mx, __shfl_xor(mx, off));

  // pass 2: sum of exp (in-wave)
  float sm = 0.f;
  for (int e = rs + l; e < re; e += 64)
    sm += expf(lrelu02(as_[(size_t)col[e] * 4 + wv] + adn) - mx);
#pragma unroll
  for (int off = 32; off > 0; off >>= 1)
    sm += __shfl_xor(sm, off);
  const float Sinv = 1.f / (sm + 1e-16f);

  // pass 3: gather; lane owns cols wv*256 + 4l .. +3 ; unroll-6 MLP
  const int cb = wv * 256 + 4 * l;
  float acc[4] = {0.f, 0.f, 0.f, 0.f};
  for (int c0 = rs; c0 < re; c0 += 64) {
    const int idx = c0 + l;
    float w_l = 0.f;
    int s_l = 0;
    if (idx < re) {
      s_l = col[idx];
      w_l = expf(lrelu02(as_[(size_t)s_l * 4 + wv] + adn) - mx) * Sinv;
    }
    const int cnt = min(64, re - c0);
    int e = 0;
    for (; e + 5 < cnt; e += 6) {
      float w0 = __shfl(w_l, e + 0), w1 = __shfl(w_l, e + 1);
      float w2 = __shfl(w_l, e + 2), w3 = __shfl(w_l, e + 3);
      float w4 = __shfl(w_l, e + 4), w5 = __shfl(w_l, e + 5);
      int s0 = __shfl(s_l, e + 0), s1 = __shfl(s_l, e + 1);
      int s2 = __shfl(s_l, e + 2), s3 = __shfl(s_l, e + 3);
      int s4 = __shfl(s_l, e + 4), s5 = __shfl(s_l, e + 5);
      half4v h0 = *(const half4v*)(h + (size_t)s0 * NPROJ + cb);
      half4v h1 = *(const half4v*)(h + (size_t)s1 * NPROJ + cb);
      half4v h2 = *(const half4v*)(h + (size_t)s2 * NPROJ + cb);
      half4v h3 = *(const half4v*)(h + (size_t)s3 * NPROJ + cb);
      half4v h4 = *(const half4v*)(h + (size_t)s4 * NPROJ + cb);
      half4v h5 = *(const half4v*)(h + (size_t)s5 * NPROJ + cb);
#pragma unroll
      for (int j = 0; j < 4; ++j) {
        acc[j] = fmaf(w0, (float)h0[j], acc[j]);
        acc[j] = fmaf(w1, (float)h1[j], acc[j]);
        acc[j] = fmaf(w2, (float)h2[j], acc[j]);
        acc[j] = fmaf(w3, (float)h3[j], acc[j]);
        acc[j] = fmaf(w4, (float)h4[j], acc[j]);
        acc[j] = fmaf(w5, (float)h5[j], acc[j]);
      }
    }
    for (; e < cnt; ++e) {
      const float w = __shfl(w_l, e);
      const int s = __shfl(s_l, e);
      half4v hv = *(const half4v*)(h + (size_t)s * NPROJ + cb);
      acc[0] = fmaf(w, (float)hv[0], acc[0]);
      acc[1] = fmaf(w, (float)hv[1], acc[1]);
      acc[2] = fmaf(w, (float)hv[2], acc[2]);
      acc[3] = fmaf(w, (float)hv[3], acc[3]);
    }
  }

  // epilogue: bias, ELU, residual; LayerNorm stats
  const size_t base = (size_t)n * NPROJ + cb;
  float4 b4 = *(const float4*)(bias + cb);
  float bb[4] = {b4.x, b4.y, b4.z, b4.w};
  half4v xhv = *(const half4v*)(xh + base);
  half4v xlv = *(const half4v*)(xl + base);
  float v[4];
  float sum = 0.f, sumsq = 0.f;
#pragma unroll
  for (int j = 0; j < 4; ++j) {
    float u = acc[j] + bb[j];
    u = u > 0.f ? u : expm1f(u);
    u += (float)xhv[j] + (float)xlv[j];
    v[j] = u;
    sum += u;
    sumsq += u * u;
  }
#pragma unroll
  for (int off = 32; off > 0; off >>= 1) {
    sum += __shfl_xor(sum, off);
    sumsq += __shfl_xor(sumsq, off);
  }
  if (l == 0) {
    sred[wv] = sum;
    sred[4 + wv] = sumsq;
  }
  __syncthreads();
  const float tsum = sred[0] + sred[1] + sred[2] + sred[3];
  const float tssq = sred[4] + sred[5] + sred[6] + sred[7];
  const float mu = tsum * (1.f / 1024.f);
  const float var = tssq * (1.f / 1024.f) - mu * mu;
  const float rstd = rsqrtf(var + 1e-5f);

  float4 g4 = *(const float4*)(gamma + cb);
  float4 e4 = *(const float4*)(beta + cb);
  float gg[4] = {g4.x, g4.y, g4.z, g4.w};
  float ee[4] = {e4.x, e4.y, e4.z, e4.w};
  half4v oh, ol;
#pragma unroll
  for (int j = 0; j < 4; ++j) {
    float y = (v[j] - mu) * rstd * gg[j] + ee[j];
    _Float16 hh = (_Float16)y;
    oh[j] = hh;
    ol[j] = (_Float16)(y - (float)hh);
  }
  *(half4v*)(xh + base) = oh;
  *(half4v*)(xl + base) = ol;
}

// ============================================================
// pooling + classifier
// ============================================================
__global__ void k_scores(const float* __restrict__ tb,
                         const float* __restrict__ W2,
                         const float* __restrict__ b2,
                         float* __restrict__ scores, int N) {
  int n = blockIdx.x, lane = threadIdx.x;
  float s = 0.f;
  for (int k = lane; k < 512; k += 64) s = fmaf(tb[(size_t)n * 512 + k], W2[k], s);
  for (int off = 32; off > 0; off >>= 1) s += __shfl_down(s, off);
  if (lane == 0) scores[n] = s + b2[0];
}

__global__ void k_grange_init(int* gstart, int* gend, int N) {
  int g = threadIdx.x;
  if (g < NGRAPH) { gstart[g] = N; gend[g] = 0; }
}

__global__ void k_grange_mark(const int* __restrict__ batch, int* gstart,
                              int* gend, int N) {
  int n = blockIdx.x * 256 + threadIdx.x;
  if (n >= N) return;
  int b = batch[n];
  if (n == 0 || batch[n - 1] != b) gstart[b] = n;
  if (n == N - 1 || batch[n + 1] != b) gend[b] = n + 1;
}

__global__ __launch_bounds__(256) void k_pool(
    const float* __restrict__ scores, const _Float16* __restrict__ xh,
    const _Float16* __restrict__ xl, const int* __restrict__ gstart,
    const int* __restrict__ gend, float* __restrict__ pooled) {
  __shared__ float red[256];
  __shared__ float wt[256];
  __shared__ float m_s, s_s;
  int g = blockIdx.x, t = threadIdx.x;
  int rs = gstart[g], re = gend[g];

  float mx = -1e30f;
  for (int i = rs + t; i < re; i += 256) mx = fmaxf(mx, scores[i]);
  red[t] = mx;
  __syncthreads();
  for (int s = 128; s > 0; s >>= 1) {
    if (t < s) red[t] = fmaxf(red[t], red[t + s]);
    __syncthreads();
  }
  if (t == 0) m_s = red[0];
  __syncthreads();
  float m = m_s;

  float sm = 0.f;
  for (int i = rs + t; i < re; i += 256) sm += expf(scores[i] - m);
  red[t] = sm;
  __syncthreads();
  for (int s = 128; s > 0; s >>= 1) {
    if (t < s) red[t] += red[t + s];
    __syncthreads();
  }
  if (t == 0) s_s = red[0] + 1e-16f;
  __syncthreads();
  float sden = s_s;

  float acc[4] = {0.f, 0.f, 0.f, 0.f};
  for (int c0 = rs; c0 < re; c0 += 256) {
    int cnt = min(256, re - c0);
    if (t < cnt) wt[t] = expf(scores[c0 + t] - m) / sden;
    __syncthreads();
    for (int e = 0; e < cnt; ++e) {
      float w = wt[e];
      size_t base = (size_t)(c0 + e) * NPROJ + 4 * t;
      half4v hv = *(const half4v*)(xh + base);
      half4v lv = *(const half4v*)(xl + base);
#pragma unroll
      for (int j = 0; j < 4; ++j)
        acc[j] = fmaf(w, (float)hv[j] + (float)lv[j], acc[j]);
    }
    __syncthreads();
  }
#pragma unroll
  for (int j = 0; j < 4; ++j) pooled[(size_t)g * NPROJ + 4 * t + j] = acc[j];
}

__global__ __launch_bounds__(256) void k_cls1(const float* __restrict__ pooled,
                                              const float* __restrict__ W1,
                                              const float* __restrict__ b1,
                                              float* __restrict__ hid) {
  __shared__ float p[1024];
  int g = blockIdx.y;
  int colc = blockIdx.x * 256 + threadIdx.x;
  for (int k = threadIdx.x; k < 1024; k += 256) p[k] = pooled[(size_t)g * 1024 + k];
  __syncthreads();
  float s = 0.f;
  for (int k = 0; k < 1024; ++k) s = fmaf(p[k], W1[(size_t)k * 512 + colc], s);
  s += b1[colc];
  s = 0.5f * s * (1.f + erff(s * 0.70710678118654752f));
  hid[(size_t)g * 512 + colc] = s;
}

__global__ void k_cls2(const float* __restrict__ hid,
                       const float* __restrict__ W2,
                       const float* __restrict__ b2, float* __restrict__ out) {
  int o = blockIdx.x, g = blockIdx.y, lane = threadIdx.x;
  float s = 0.f;
  for (int k = lane; k < 512; k += 64) s = fmaf(hid[(size_t)g * 512 + k], W2[k * 14 + o], s);
  for (int off = 32; off > 0; off >>= 1) s += __shfl_down(s, off);
  if (lane == 0) out[g * 14 + o] = s + b2[o];
}

// ============================================================
extern "C" void kernel_launch(void* const* d_in, const int* in_sizes, int n_in,
                              void* d_out, int out_size, void* d_ws, size_t ws_size,
                              hipStream_t stream) {
  const float* x_in   = (const float*)d_in[0];
  const int*   eidx   = (const int*)d_in[1];
  const int*   batch  = (const int*)d_in[2];
  const float* proj_W = (const float*)d_in[3];
  const float* proj_b = (const float*)d_in[4];
  const float* gat_W  = (const float*)d_in[5];
  const float* a_src  = (const float*)d_in[6];
  const float* a_dst  = (const float*)d_in[7];
  const float* gat_b  = (const float*)d_in[8];
  const float* gamma  = (const float*)d_in[9];
  const float* beta   = (const float*)d_in[10];
  const float* pW1    = (const float*)d_in[11];
  const float* pb1    = (const float*)d_in[12];
  const float* pW2    = (const float*)d_in[13];
  const float* pb2    = (const float*)d_in[14];
  const float* cW1    = (const float*)d_in[15];
  const float* cb1    = (const float*)d_in[16];
  const float* cW2    = (const float*)d_in[17];
  const float* cb2    = (const float*)d_in[18];
  float* out = (float*)d_out;

  const int N = in_sizes[0] / NPROJ;  // 10000
  const int E = in_sizes[1] / 2;      // 160000
  const int Etot = E + N;
  const int NB = (N + 255) / 256;     // 40 scan blocks

  char* ws = (char*)d_ws;
  size_t off = 0;
  auto alloc = [&](size_t bytes) -> void* {
    void* p = ws + off;
    off = (off + bytes + 255) & ~(size_t)255;
    return p;
  };
  _Float16* xh   = (_Float16*)alloc((size_t)N * NPROJ * 2);
  _Float16* xl   = (_Float16*)alloc((size_t)N * NPROJ * 2);
  _Float16* hf   = (_Float16*)alloc((size_t)N * NPROJ * 2);   // f16 h
  float*    hb   = (float*)alloc((size_t)N * NPROJ * 4);      // in-f16 / tb
  _Float16* pjh  = (_Float16*)alloc((size_t)NPROJ * NPROJ * 2);
  _Float16* gwh  = (_Float16*)alloc((size_t)3 * NPROJ * NPROJ * 2);
  _Float16* pwh  = (_Float16*)alloc((size_t)512 * NPROJ * 2);
  float* asb     = (float*)alloc((size_t)N * 4 * 4);
  float* adb     = (float*)alloc((size_t)N * 4 * 4);
  int*   cnt     = (int*)alloc((size_t)N * 4);
  int*   bsum    = (int*)alloc(64 * 4);
  int*   rowst   = (int*)alloc((size_t)(N + 1) * 4);
  int*   cursor  = (int*)alloc((size_t)N * 4);
  int*   ccol    = (int*)alloc((size_t)Etot * 4);
  float* scores  = (float*)alloc((size_t)N * 4);
  int*   gstart  = (int*)alloc(NGRAPH * 4);
  int*   gend    = (int*)alloc(NGRAPH * 4);
  float* pooled  = (float*)alloc((size_t)NGRAPH * NPROJ * 4);
  float* hid     = (float*)alloc((size_t)NGRAPH * 512 * 4);

  const int* esrc = eidx;
  const int* edst = eidx + E;

  // ---- CSR by dst (3-level scan) ----
  k_init_counts<<<NB, 256, 0, stream>>>(cnt, N);
  k_count<<<(E + 255) / 256, 256, 0, stream>>>(edst, cnt, E);
  k_scan1<<<NB, 256, 0, stream>>>(cnt, bsum, N);
  k_scan2<<<1, 64, 0, stream>>>(bsum, NB);
  k_scan3<<<NB, 256, 0, stream>>>(cnt, bsum, rowst, cursor, N, Etot);
  k_fill<<<(E + 255) / 256, 256, 0, stream>>>(esrc, edst, cursor, ccol, E);
  k_fill_self<<<NB, 256, 0, stream>>>(cursor, ccol, N);

  // ---- weight transposes (f16 hi) ----
  k_transT<<<dim3(32, 32), 256, 0, stream>>>(proj_W, pjh, NPROJ, NPROJ);
  for (int i = 0; i < 3; ++i)
    k_transT<<<dim3(32, 32), 256, 0, stream>>>(gat_W + (size_t)i * NPROJ * NPROJ,
                                               gwh + (size_t)i * NPROJ * NPROJ,
                                               NPROJ, NPROJ);
  k_transT<<<dim3(16, 32), 256, 0, stream>>>(pW1, pwh, NPROJ, 512);

  // ---- input f16 (scratch inside hb) + projection ----
  _Float16* inh = (_Float16*)hb;
  k_tof16<<<((N * NPROJ / 8) + 255) / 256, 256, 0, stream>>>(x_in, inh,
                                                             N * NPROJ / 8);
  const int MB = (N + 127) / 128;       // 79
  const int mpad8 = (MB + 7) / 8;       // 10
  const dim3 grid8(8 * mpad8 * 8);      // Nc=1024: lgn=3
  const dim3 grid4(4 * mpad8 * 8);      // Nc=512:  lgn=2
  gemm_mfma<0, 1><<<grid8, 256, 0, stream>>>(
      inh, pjh, proj_b, nullptr, xh, xl, N, NPROJ, 3, mpad8);

  // ---- 3 GAT layers ----
  for (int i = 0; i < 3; ++i) {
    gemm_mfma<0, 2><<<grid8, 256, 0, stream>>>(
        xh, gwh + (size_t)i * NPROJ * NPROJ,
        nullptr, nullptr, hf, nullptr, N, NPROJ, 3, mpad8);
    k_alpha<<<(N + 1) / 2, 256, 0, stream>>>(hf, a_src + i * NPROJ,
                                             a_dst + i * NPROJ, asb, adb, N);
    k_aggregate_ln<<<N, 256, 0, stream>>>(hf, asb, adb, rowst, ccol,
                                          gat_b + i * NPROJ, gamma + i * NPROJ,
                                          beta + i * NPROJ, xh, xl);
  }

  // ---- attention pooling ----
  float* tb = hb;  // N x 512 f32
  gemm_mfma<1, 0><<<grid4, 256, 0, stream>>>(
      xh, pwh, pb1, tb, nullptr, nullptr, N, 512, 2, mpad8);
  k_scores<<<N, 64, 0, stream>>>(tb, pW2, pb2, scores, N);
  k_grange_init<<<1, 64, 0, stream>>>(gstart, gend, N);
  k_grange_mark<<<NB, 256, 0, stream>>>(batch, gstart, gend, N);
  k_pool<<<NGRAPH, 256, 0, stream>>>(scores, xh, xl, gstart, gend, pooled);

  // ---- classifier ----
  k_cls1<<<dim3(2, NGRAPH), 256, 0, stream>>>(pooled, cW1, cb1, hid);
  k_cls2<<<dim3(14, NGRAPH), 64, 0, stream>>>(hid, cW2, cb2, out);
}

// Round 13
// 482.833 us; speedup vs baseline: 1.2338x; 1.0024x over previous
//
#include <hip/hip_runtime.h>
#include <hip/hip_bf16.h>
#include <hip/hip_fp16.h>
#include <math.h>

#define NPROJ 1024
#define NHEADS 4
#define NHID 256
#define NGRAPH 64

typedef _Float16 half8 __attribute__((ext_vector_type(8)));
typedef _Float16 half4v __attribute__((ext_vector_type(4)));
typedef float floatx4 __attribute__((ext_vector_type(4)));

#define GLD_LDS16(g, l)                                                        \
  __builtin_amdgcn_global_load_lds(                                            \
      (const __attribute__((address_space(1))) unsigned int*)(g),              \
      (__attribute__((address_space(3))) unsigned int*)(l), 16, 0, 0)

// ============================================================
// Single-product f16 MFMA GEMM:  C = A @ BT^T   (K fixed = 1024)
// A: M x 1024 f16 (hi of fp32).  B TRANSPOSED: Nc x 1024 f16 (hi of fp32).
// 128x128 tile, BK=64, 4 waves (2x2), wave 64x64, 16x16x32 MFMA.
// LDS = 2 x 16KB = 32KB -> 4 blocks/CU; grid 640 fits one residency round.
// Single-buffer overlap: frags->regs, barrier, STAGE(t+1) under MFMAs.
// XOR-swizzled LDS via pre-swizzled global source.
// XCD-chunked grid: each XCD owns mpad8 contiguous row-slabs, bx fastest.
// ============================================================
template<int ACT, int OUT>  // ACT: 0 none, 1 tanh; OUT: 0 f32, 1 split pair, 2 f16
__global__ __launch_bounds__(256, 4) void gemm_mfma(
    const _Float16* __restrict__ A, const _Float16* __restrict__ BT,
    const float* __restrict__ bias, float* __restrict__ Cf,
    _Float16* __restrict__ Ch, _Float16* __restrict__ Cl,
    int M, int Nc, int lgn, int mpad8)
{
  __shared__ __align__(16) _Float16 ldsA[128 * 64];
  __shared__ __align__(16) _Float16 ldsB[128 * 64];

  const int id  = blockIdx.x;
  const int xcd = id & 7;
  const int kk  = id >> 3;
  const int bx  = kk & ((1 << lgn) - 1);
  const int by  = xcd * mpad8 + (kk >> lgn);
  const int m0  = by * 128, n0 = bx * 128;
  if (m0 >= M) return;

  const int tid  = threadIdx.x;
  const int lane = tid & 63;
  const int wave = tid >> 6;
  const int wm = wave >> 1, wn = wave & 1;

  const int srow = tid >> 3;                              // + r*32
  const int kc8  = (((tid & 7) ^ ((tid >> 3) & 7)) << 3); // logical k elems
  const int wb16 = (tid & ~63) * 16;                      // wave-uniform base

  floatx4 acc[4][4] = {};

  const int l15 = lane & 15;
  const int swz = (l15 & 7) << 4;
  const int kbyte0 = (lane >> 4) * 16;

  auto STAGE = [&](int t) {
    const int k0 = t << 6;
#pragma unroll
    for (int r = 0; r < 4; ++r) {
      int rowA = m0 + r * 32 + srow;
      rowA = rowA < M ? rowA : (M - 1);
      GLD_LDS16(A + (size_t)rowA * 1024 + k0 + kc8,
                (char*)ldsA + r * 4096 + wb16);
      GLD_LDS16(BT + (size_t)(n0 + r * 32 + srow) * 1024 + k0 + kc8,
                (char*)ldsB + r * 4096 + wb16);
    }
  };

  STAGE(0);
  __syncthreads();

  for (int t = 0; t < 16; ++t) {
    const int koff0 = kbyte0 ^ swz;
    half8 a0[4], b0[4];
#pragma unroll
    for (int i = 0; i < 4; ++i)
      a0[i] = *(const half8*)((const char*)ldsA +
                              (wm * 64 + i * 16 + l15) * 128 + koff0);
#pragma unroll
    for (int j = 0; j < 4; ++j)
      b0[j] = *(const half8*)((const char*)ldsB +
                              (wn * 64 + j * 16 + l15) * 128 + koff0);
#pragma unroll
    for (int i = 0; i < 4; ++i)
#pragma unroll
      for (int j = 0; j < 4; ++j)
        acc[i][j] = __builtin_amdgcn_mfma_f32_16x16x32_f16(a0[i], b0[j],
                                                           acc[i][j], 0, 0, 0);

    const int koff1 = (64 + kbyte0) ^ swz;
    half8 a1[4], b1[4];
#pragma unroll
    for (int i = 0; i < 4; ++i)
      a1[i] = *(const half8*)((const char*)ldsA +
                              (wm * 64 + i * 16 + l15) * 128 + koff1);
#pragma unroll
    for (int j = 0; j < 4; ++j)
      b1[j] = *(const half8*)((const char*)ldsB +
                              (wn * 64 + j * 16 + l15) * 128 + koff1);
    __syncthreads();            // all LDS reads of tile t complete (regs held)
    if (t < 15) STAGE(t + 1);   // overwrite LDS under the MFMAs below

#pragma unroll
    for (int i = 0; i < 4; ++i)
#pragma unroll
      for (int j = 0; j < 4; ++j)
        acc[i][j] = __builtin_amdgcn_mfma_f32_16x16x32_f16(a1[i], b1[j],
                                                           acc[i][j], 0, 0, 0);

    if (t < 15) __syncthreads();  // vmcnt drain (mostly hidden by MFMAs)
  }

  // epilogue: C[row = (lane>>4)*4 + reg, col = lane&15] per 16x16 frag
  const int rbase = (lane >> 4) * 4;
#pragma unroll
  for (int j = 0; j < 4; ++j) {
    const int col = n0 + wn * 64 + j * 16 + l15;
    const float bv = bias ? bias[col] : 0.f;
#pragma unroll
    for (int i = 0; i < 4; ++i) {
      const int gm0 = m0 + wm * 64 + i * 16 + rbase;
#pragma unroll
      for (int r = 0; r < 4; ++r) {
        const int gm = gm0 + r;
        if (gm >= M) continue;
        float v = acc[i][j][r] + bv;
        if (ACT == 1) v = tanhf(v);
        if (OUT == 1) {
          _Float16 hh = (_Float16)v;
          Ch[(size_t)gm * Nc + col] = hh;
          Cl[(size_t)gm * Nc + col] = (_Float16)(v - (float)hh);
        } else if (OUT == 2) {
          Ch[(size_t)gm * Nc + col] = (_Float16)v;
        } else {
          Cf[(size_t)gm * Nc + col] = v;
        }
      }
    }
  }
}

// ============================================================
// converters
// ============================================================
__global__ void k_tof16(const float* __restrict__ in, _Float16* __restrict__ h,
                        int L8) {
  int i = blockIdx.x * 256 + threadIdx.x;
  if (i >= L8) return;
  const float4* p = (const float4*)(in + (size_t)i * 8);
  float4 v0 = p[0], v1 = p[1];
  float vv[8] = {v0.x, v0.y, v0.z, v0.w, v1.x, v1.y, v1.z, v1.w};
  half8 hv;
#pragma unroll
  for (int j = 0; j < 8; ++j) hv[j] = (_Float16)vv[j];
  *(half8*)(h + (size_t)i * 8) = hv;
}

// W (K x Nc) fp32 -> transposed (Nc x K) f16
__global__ __launch_bounds__(256) void k_transT(const float* __restrict__ in,
                                                _Float16* __restrict__ hT,
                                                int K, int Nc) {
  __shared__ float t[32][33];
  const int tx = threadIdx.x & 31, ty = threadIdx.x >> 5;
  const int c0 = blockIdx.x * 32, k0 = blockIdx.y * 32;
#pragma unroll
  for (int r = 0; r < 4; ++r)
    t[ty + 8 * r][tx] = in[(size_t)(k0 + ty + 8 * r) * Nc + c0 + tx];
  __syncthreads();
#pragma unroll
  for (int r = 0; r < 4; ++r) {
    float v = t[tx][ty + 8 * r];
    int oc = c0 + ty + 8 * r;
    hT[(size_t)oc * K + k0 + tx] = (_Float16)v;
  }
}

// ============================================================
// CSR-by-dst construction (recomputed every call; no caching)
// 3-level scan
// ============================================================
__global__ void k_init_counts(int* cnt, int n) {
  int i = blockIdx.x * 256 + threadIdx.x;
  if (i < n) cnt[i] = 1;  // self-loop pre-counted
}

__global__ void k_count(const int* __restrict__ dst, int* cnt, int e) {
  int i = blockIdx.x * 256 + threadIdx.x;
  if (i < e) atomicAdd(&cnt[dst[i]], 1);
}

__global__ __launch_bounds__(256) void k_scan1(int* __restrict__ cnt,
                                               int* __restrict__ bsum, int n) {
  __shared__ int wsum[4];
  const int b = blockIdx.x, t = threadIdx.x, i = b * 256 + t;
  const int x = (i < n) ? cnt[i] : 0;
  int v = x;
#pragma unroll
  for (int off = 1; off < 64; off <<= 1) {
    int u = __shfl_up(v, off);
    if ((t & 63) >= off) v += u;
  }
  if ((t & 63) == 63) wsum[t >> 6] = v;
  __syncthreads();
  int wo = 0;
#pragma unroll
  for (int w = 0; w < 4; ++w) wo += (w < (t >> 6)) ? wsum[w] : 0;
  const int incl = v + wo;
  if (i < n) cnt[i] = incl - x;
  if (t == 255) bsum[b] = incl;
}

__global__ void k_scan2(int* __restrict__ bsum, int nb) {
  const int t = threadIdx.x;
  const int x = (t < nb) ? bsum[t] : 0;
  int v = x;
#pragma unroll
  for (int off = 1; off < 64; off <<= 1) {
    int u = __shfl_up(v, off);
    if (t >= off) v += u;
  }
  if (t < nb) bsum[t] = v - x;
}

__global__ void k_scan3(const int* __restrict__ cnt, const int* __restrict__ bsum,
                        int* __restrict__ rowstart, int* __restrict__ cursor,
                        int n, int etot) {
  const int i = blockIdx.x * 256 + threadIdx.x;
  if (i < n) {
    const int v = cnt[i] + bsum[i >> 8];
    rowstart[i] = v;
    cursor[i] = v;
  }
  if (i == 0) rowstart[n] = etot;
}

__global__ void k_fill(const int* __restrict__ src, const int* __restrict__ dst,
                       int* cursor, int* __restrict__ col, int e) {
  int i = blockIdx.x * 256 + threadIdx.x;
  if (i < e) {
    int p = atomicAdd(&cursor[dst[i]], 1);
    col[p] = src[i];
  }
}

__global__ void k_fill_self(int* cursor, int* __restrict__ col, int n) {
  int i = blockIdx.x * 256 + threadIdx.x;
  if (i < n) {
    int p = atomicAdd(&cursor[i], 1);
    col[p] = i;
  }
}

// ============================================================
// per-node attention logits (f16 h): half8 loads, 2 heads/wave,
// 2 nodes per 256-thread block
// ============================================================
__global__ __launch_bounds__(256) void k_alpha(
    const _Float16* __restrict__ h, const float* __restrict__ a_src,
    const float* __restrict__ a_dst, float* __restrict__ as_out,
    float* __restrict__ ad_out, int N) {
  const int t = threadIdx.x;
  const int w = t >> 6, l = t & 63;
  const int node = blockIdx.x * 2 + (w >> 1);
  if (node >= N) return;
  const int head = (w & 1) * 2 + (l >> 5);
  const int cb = head * 256 + (l & 31) * 8;
  half8 v = *(const half8*)(h + (size_t)node * NPROJ + cb);
  float4 s0 = *(const float4*)(a_src + cb);
  float4 s1 = *(const float4*)(a_src + cb + 4);
  float4 d0 = *(const float4*)(a_dst + cb);
  float4 d1 = *(const float4*)(a_dst + cb + 4);
  float sv[8] = {s0.x, s0.y, s0.z, s0.w, s1.x, s1.y, s1.z, s1.w};
  float dv[8] = {d0.x, d0.y, d0.z, d0.w, d1.x, d1.y, d1.z, d1.w};
  float ss = 0.f, sd = 0.f;
#pragma unroll
  for (int j = 0; j < 8; ++j) {
    float f = (float)v[j];
    ss = fmaf(f, sv[j], ss);
    sd = fmaf(f, dv[j], sd);
  }
#pragma unroll
  for (int off = 1; off <= 16; off <<= 1) {
    ss += __shfl_xor(ss, off);
    sd += __shfl_xor(sd, off);
  }
  if ((l & 31) == 0) {
    as_out[node * 4 + head] = ss;
    ad_out[node * 4 + head] = sd;
  }
}

// ============================================================
// fused segment-softmax + aggregation + bias/ELU/residual/LayerNorm
// r11 form: wave-per-head, in-wave shfl softmax, unroll-4 gather
// (proven 62.5 us, 28 VGPR, 70% occupancy)
// ============================================================
__device__ __forceinline__ float lrelu02(float x) {
  return x > 0.f ? x : 0.2f * x;
}

__global__ __launch_bounds__(256) void k_aggregate_ln(
    const _Float16* __restrict__ h, const float* __restrict__ as_,
    const float* __restrict__ ad_, const int* __restrict__ rowstart,
    const int* __restrict__ col, const float* __restrict__ bias,
    const float* __restrict__ gamma, const float* __restrict__ beta,
    _Float16* __restrict__ xh, _Float16* __restrict__ xl) {
  __shared__ float sred[8];

  const int n = blockIdx.x, t = threadIdx.x;
  const int wv = t >> 6, l = t & 63;
  const int rs = rowstart[n], re = rowstart[n + 1];
  const float adn = ad_[n * 4 + wv];

  // pass 1: per-head max (in-wave)
  float mx = -1e30f;
  for (int e = rs + l; e < re; e += 64)
    mx = fmaxf(mx, lrelu02(as_[(size_t)col[e] * 4 + wv] + adn));
#pragma unroll
  for (int off = 32; off > 0; off >>= 1)
    mx = fmaxf(mx, __shfl_xor(mx, off));

  // pass 2: sum of exp (in-wave)
  float sm = 0.f;
  for (int e = rs + l; e < re; e += 64)
    sm += expf(lrelu02(as_[(size_t)col[e] * 4 + wv] + adn) - mx);
#pragma unroll
  for (int off = 32; off > 0; off >>= 1)
    sm += __shfl_xor(sm, off);
  const float Sinv = 1.f / (sm + 1e-16f);

  // pass 3: gather; lane owns cols wv*256 + 4l .. +3 ; unroll-4 MLP
  const int cb = wv * 256 + 4 * l;
  float acc[4] = {0.f, 0.f, 0.f, 0.f};
  for (int c0 = rs; c0 < re; c0 += 64) {
    const int idx = c0 + l;
    float w_l = 0.f;
    int s_l = 0;
    if (idx < re) {
      s_l = col[idx];
      w_l = expf(lrelu02(as_[(size_t)s_l * 4 + wv] + adn) - mx) * Sinv;
    }
    const int cnt = min(64, re - c0);
    int e = 0;
    for (; e + 3 < cnt; e += 4) {
      float w0 = __shfl(w_l, e + 0), w1 = __shfl(w_l, e + 1);
      float w2 = __shfl(w_l, e + 2), w3 = __shfl(w_l, e + 3);
      int s0 = __shfl(s_l, e + 0), s1 = __shfl(s_l, e + 1);
      int s2 = __shfl(s_l, e + 2), s3 = __shfl(s_l, e + 3);
      half4v h0 = *(const half4v*)(h + (size_t)s0 * NPROJ + cb);
      half4v h1 = *(const half4v*)(h + (size_t)s1 * NPROJ + cb);
      half4v h2 = *(const half4v*)(h + (size_t)s2 * NPROJ + cb);
      half4v h3 = *(const half4v*)(h + (size_t)s3 * NPROJ + cb);
#pragma unroll
      for (int j = 0; j < 4; ++j) {
        acc[j] = fmaf(w0, (float)h0[j], acc[j]);
        acc[j] = fmaf(w1, (float)h1[j], acc[j]);
        acc[j] = fmaf(w2, (float)h2[j], acc[j]);
        acc[j] = fmaf(w3, (float)h3[j], acc[j]);
      }
    }
    for (; e < cnt; ++e) {
      const float w = __shfl(w_l, e);
      const int s = __shfl(s_l, e);
      half4v hv = *(const half4v*)(h + (size_t)s * NPROJ + cb);
      acc[0] = fmaf(w, (float)hv[0], acc[0]);
      acc[1] = fmaf(w, (float)hv[1], acc[1]);
      acc[2] = fmaf(w, (float)hv[2], acc[2]);
      acc[3] = fmaf(w, (float)hv[3], acc[3]);
    }
  }

  // epilogue: bias, ELU, residual; LayerNorm stats
  const size_t base = (size_t)n * NPROJ + cb;
  float4 b4 = *(const float4*)(bias + cb);
  float bb[4] = {b4.x, b4.y, b4.z, b4.w};
  half4v xhv = *(const half4v*)(xh + base);
  half4v xlv = *(const half4v*)(xl + base);
  float v[4];
  float sum = 0.f, sumsq = 0.f;
#pragma unroll
  for (int j = 0; j < 4; ++j) {
    float u = acc[j] + bb[j];
    u = u > 0.f ? u : expm1f(u);
    u += (float)xhv[j] + (float)xlv[j];
    v[j] = u;
    sum += u;
    sumsq += u * u;
  }
#pragma unroll
  for (int off = 32; off > 0; off >>= 1) {
    sum += __shfl_xor(sum, off);
    sumsq += __shfl_xor(sumsq, off);
  }
  if (l == 0) {
    sred[wv] = sum;
    sred[4 + wv] = sumsq;
  }
  __syncthreads();
  const float tsum = sred[0] + sred[1] + sred[2] + sred[3];
  const float tssq = sred[4] + sred[5] + sred[6] + sred[7];
  const float mu = tsum * (1.f / 1024.f);
  const float var = tssq * (1.f / 1024.f) - mu * mu;
  const float rstd = rsqrtf(var + 1e-5f);

  float4 g4 = *(const float4*)(gamma + cb);
  float4 e4 = *(const float4*)(beta + cb);
  float gg[4] = {g4.x, g4.y, g4.z, g4.w};
  float ee[4] = {e4.x, e4.y, e4.z, e4.w};
  half4v oh, ol;
#pragma unroll
  for (int j = 0; j < 4; ++j) {
    float y = (v[j] - mu) * rstd * gg[j] + ee[j];
    _Float16 hh = (_Float16)y;
    oh[j] = hh;
    ol[j] = (_Float16)(y - (float)hh);
  }
  *(half4v*)(xh + base) = oh;
  *(half4v*)(xl + base) = ol;
}

// ============================================================
// pooling + classifier
// ============================================================
__global__ void k_scores(const float* __restrict__ tb,
                         const float* __restrict__ W2,
                         const float* __restrict__ b2,
                         float* __restrict__ scores, int N) {
  int n = blockIdx.x, lane = threadIdx.x;
  float s = 0.f;
  for (int k = lane; k < 512; k += 64) s = fmaf(tb[(size_t)n * 512 + k], W2[k], s);
  for (int off = 32; off > 0; off >>= 1) s += __shfl_down(s, off);
  if (lane == 0) scores[n] = s + b2[0];
}

__global__ void k_grange_init(int* gstart, int* gend, int N) {
  int g = threadIdx.x;
  if (g < NGRAPH) { gstart[g] = N; gend[g] = 0; }
}

__global__ void k_grange_mark(const int* __restrict__ batch, int* gstart,
                              int* gend, int N) {
  int n = blockIdx.x * 256 + threadIdx.x;
  if (n >= N) return;
  int b = batch[n];
  if (n == 0 || batch[n - 1] != b) gstart[b] = n;
  if (n == N - 1 || batch[n + 1] != b) gend[b] = n + 1;
}

// per-graph softmax over scores -> normalized weights (in place)
__global__ __launch_bounds__(256) void k_poolw(
    float* __restrict__ scores, const int* __restrict__ gstart,
    const int* __restrict__ gend) {
  __shared__ float red[256];
  __shared__ float m_s, s_s;
  int g = blockIdx.x, t = threadIdx.x;
  int rs = gstart[g], re = gend[g];

  float mx = -1e30f;
  for (int i = rs + t; i < re; i += 256) mx = fmaxf(mx, scores[i]);
  red[t] = mx;
  __syncthreads();
  for (int s = 128; s > 0; s >>= 1) {
    if (t < s) red[t] = fmaxf(red[t], red[t + s]);
    __syncthreads();
  }
  if (t == 0) m_s = red[0];
  __syncthreads();
  float m = m_s;

  float sm = 0.f;
  for (int i = rs + t; i < re; i += 256) sm += expf(scores[i] - m);
  red[t] = sm;
  __syncthreads();
  for (int s = 128; s > 0; s >>= 1) {
    if (t < s) red[t] += red[t + s];
    __syncthreads();
  }
  if (t == 0) s_s = red[0] + 1e-16f;
  __syncthreads();
  float sinv = 1.f / s_s;

  for (int i = rs + t; i < re; i += 256)
    scores[i] = expf(scores[i] - m) * sinv;
}

// weighted segment sum: grid (NGRAPH, 4); block (g,q) covers cols
// q*256..q*256+255; 4 waves node-stride-4, lane owns 4 cols (8B loads)
__global__ __launch_bounds__(256) void k_pool2(
    const float* __restrict__ w, const _Float16* __restrict__ xh,
    const _Float16* __restrict__ xl, const int* __restrict__ gstart,
    const int* __restrict__ gend, float* __restrict__ pooled) {
  __shared__ float red[3][64][4];
  const int g = blockIdx.x, q = blockIdx.y;
  const int t = threadIdx.x, wv = t >> 6, l = t & 63;
  const int rs = gstart[g], re = gend[g];
  const int cb = q * 256 + 4 * l;

  float acc[4] = {0.f, 0.f, 0.f, 0.f};
  for (int n = rs + wv; n < re; n += 4) {
    const float wn = w[n];
    const size_t base = (size_t)n * NPROJ + cb;
    half4v hv = *(const half4v*)(xh + base);
    half4v lv = *(const half4v*)(xl + base);
#pragma unroll
    for (int j = 0; j < 4; ++j)
      acc[j] = fmaf(wn, (float)hv[j] + (float)lv[j], acc[j]);
  }
  if (wv) {
#pragma unroll
    for (int j = 0; j < 4; ++j) red[wv - 1][l][j] = acc[j];
  }
  __syncthreads();
  if (wv == 0) {
#pragma unroll
    for (int k = 0; k < 3; ++k)
#pragma unroll
      for (int j = 0; j < 4; ++j) acc[j] += red[k][l][j];
    float4 o = make_float4(acc[0], acc[1], acc[2], acc[3]);
    *(float4*)(pooled + (size_t)g * NPROJ + cb) = o;
  }
}

__global__ __launch_bounds__(256) void k_cls1(const float* __restrict__ pooled,
                                              const float* __restrict__ W1,
                                              const float* __restrict__ b1,
                                              float* __restrict__ hid) {
  __shared__ float p[1024];
  int g = blockIdx.y;
  int colc = blockIdx.x * 256 + threadIdx.x;
  for (int k = threadIdx.x; k < 1024; k += 256) p[k] = pooled[(size_t)g * 1024 + k];
  __syncthreads();
  float s = 0.f;
  for (int k = 0; k < 1024; ++k) s = fmaf(p[k], W1[(size_t)k * 512 + colc], s);
  s += b1[colc];
  s = 0.5f * s * (1.f + erff(s * 0.70710678118654752f));
  hid[(size_t)g * 512 + colc] = s;
}

__global__ void k_cls2(const float* __restrict__ hid,
                       const float* __restrict__ W2,
                       const float* __restrict__ b2, float* __restrict__ out) {
  int o = blockIdx.x, g = blockIdx.y, lane = threadIdx.x;
  float s = 0.f;
  for (int k = lane; k < 512; k += 64) s = fmaf(hid[(size_t)g * 512 + k], W2[k * 14 + o], s);
  for (int off = 32; off > 0; off >>= 1) s += __shfl_down(s, off);
  if (lane == 0) out[g * 14 + o] = s + b2[o];
}

// ============================================================
extern "C" void kernel_launch(void* const* d_in, const int* in_sizes, int n_in,
                              void* d_out, int out_size, void* d_ws, size_t ws_size,
                              hipStream_t stream) {
  const float* x_in   = (const float*)d_in[0];
  const int*   eidx   = (const int*)d_in[1];
  const int*   batch  = (const int*)d_in[2];
  const float* proj_W = (const float*)d_in[3];
  const float* proj_b = (const float*)d_in[4];
  const float* gat_W  = (const float*)d_in[5];
  const float* a_src  = (const float*)d_in[6];
  const float* a_dst  = (const float*)d_in[7];
  const float* gat_b  = (const float*)d_in[8];
  const float* gamma  = (const float*)d_in[9];
  const float* beta   = (const float*)d_in[10];
  const float* pW1    = (const float*)d_in[11];
  const float* pb1    = (const float*)d_in[12];
  const float* pW2    = (const float*)d_in[13];
  const float* pb2    = (const float*)d_in[14];
  const float* cW1    = (const float*)d_in[15];
  const float* cb1    = (const float*)d_in[16];
  const float* cW2    = (const float*)d_in[17];
  const float* cb2    = (const float*)d_in[18];
  float* out = (float*)d_out;

  const int N = in_sizes[0] / NPROJ;  // 10000
  const int E = in_sizes[1] / 2;      // 160000
  const int Etot = E + N;
  const int NB = (N + 255) / 256;     // 40 scan blocks

  char* ws = (char*)d_ws;
  size_t off = 0;
  auto alloc = [&](size_t bytes) -> void* {
    void* p = ws + off;
    off = (off + bytes + 255) & ~(size_t)255;
    return p;
  };
  _Float16* xh   = (_Float16*)alloc((size_t)N * NPROJ * 2);
  _Float16* xl   = (_Float16*)alloc((size_t)N * NPROJ * 2);
  _Float16* hf   = (_Float16*)alloc((size_t)N * NPROJ * 2);   // f16 h
  float*    hb   = (float*)alloc((size_t)N * NPROJ * 4);      // in-f16 / tb
  _Float16* pjh  = (_Float16*)alloc((size_t)NPROJ * NPROJ * 2);
  _Float16* gwh  = (_Float16*)alloc((size_t)3 * NPROJ * NPROJ * 2);
  _Float16* pwh  = (_Float16*)alloc((size_t)512 * NPROJ * 2);
  float* asb     = (float*)alloc((size_t)N * 4 * 4);
  float* adb     = (float*)alloc((size_t)N * 4 * 4);
  int*   cnt     = (int*)alloc((size_t)N * 4);
  int*   bsum    = (int*)alloc(64 * 4);
  int*   rowst   = (int*)alloc((size_t)(N + 1) * 4);
  int*   cursor  = (int*)alloc((size_t)N * 4);
  int*   ccol    = (int*)alloc((size_t)Etot * 4);
  float* scores  = (float*)alloc((size_t)N * 4);
  int*   gstart  = (int*)alloc(NGRAPH * 4);
  int*   gend    = (int*)alloc(NGRAPH * 4);
  float* pooled  = (float*)alloc((size_t)NGRAPH * NPROJ * 4);
  float* hid     = (float*)alloc((size_t)NGRAPH * 512 * 4);

  const int* esrc = eidx;
  const int* edst = eidx + E;

  // ---- CSR by dst (3-level scan) ----
  k_init_counts<<<NB, 256, 0, stream>>>(cnt, N);
  k_count<<<(E + 255) / 256, 256, 0, stream>>>(edst, cnt, E);
  k_scan1<<<NB, 256, 0, stream>>>(cnt, bsum, N);
  k_scan2<<<1, 64, 0, stream>>>(bsum, NB);
  k_scan3<<<NB, 256, 0, stream>>>(cnt, bsum, rowst, cursor, N, Etot);
  k_fill<<<(E + 255) / 256, 256, 0, stream>>>(esrc, edst, cursor, ccol, E);
  k_fill_self<<<NB, 256, 0, stream>>>(cursor, ccol, N);

  // ---- weight transposes (f16 hi) ----
  k_transT<<<dim3(32, 32), 256, 0, stream>>>(proj_W, pjh, NPROJ, NPROJ);
  for (int i = 0; i < 3; ++i)
    k_transT<<<dim3(32, 32), 256, 0, stream>>>(gat_W + (size_t)i * NPROJ * NPROJ,
                                               gwh + (size_t)i * NPROJ * NPROJ,
                                               NPROJ, NPROJ);
  k_transT<<<dim3(16, 32), 256, 0, stream>>>(pW1, pwh, NPROJ, 512);

  // ---- input f16 (scratch inside hb) + projection ----
  _Float16* inh = (_Float16*)hb;
  k_tof16<<<((N * NPROJ / 8) + 255) / 256, 256, 0, stream>>>(x_in, inh,
                                                             N * NPROJ / 8);
  const int MB = (N + 127) / 128;       // 79
  const int mpad8 = (MB + 7) / 8;       // 10
  const dim3 grid8(8 * mpad8 * 8);      // Nc=1024: lgn=3
  const dim3 grid4(4 * mpad8 * 8);      // Nc=512:  lgn=2
  gemm_mfma<0, 1><<<grid8, 256, 0, stream>>>(
      inh, pjh, proj_b, nullptr, xh, xl, N, NPROJ, 3, mpad8);

  // ---- 3 GAT layers ----
  for (int i = 0; i < 3; ++i) {
    gemm_mfma<0, 2><<<grid8, 256, 0, stream>>>(
        xh, gwh + (size_t)i * NPROJ * NPROJ,
        nullptr, nullptr, hf, nullptr, N, NPROJ, 3, mpad8);
    k_alpha<<<(N + 1) / 2, 256, 0, stream>>>(hf, a_src + i * NPROJ,
                                             a_dst + i * NPROJ, asb, adb, N);
    k_aggregate_ln<<<N, 256, 0, stream>>>(hf, asb, adb, rowst, ccol,
                                          gat_b + i * NPROJ, gamma + i * NPROJ,
                                          beta + i * NPROJ, xh, xl);
  }

  // ---- attention pooling ----
  float* tb = hb;  // N x 512 f32
  gemm_mfma<1, 0><<<grid4, 256, 0, stream>>>(
      xh, pwh, pb1, tb, nullptr, nullptr, N, 512, 2, mpad8);
  k_scores<<<N, 64, 0, stream>>>(tb, pW2, pb2, scores, N);
  k_grange_init<<<1, 64, 0, stream>>>(gstart, gend, N);
  k_grange_mark<<<NB, 256, 0, stream>>>(batch, gstart, gend, N);
  k_poolw<<<NGRAPH, 256, 0, stream>>>(scores, gstart, gend);
  k_pool2<<<dim3(NGRAPH, 4), 256, 0, stream>>>(scores, xh, xl, gstart, gend,
                                               pooled);

  // ---- classifier ----
  k_cls1<<<dim3(2, NGRAPH), 256, 0, stream>>>(pooled, cW1, cb1, hid);
  k_cls2<<<dim3(14, NGRAPH), 64, 0, stream>>>(hid, cW2, cb2, out);
}

// Round 14
// 452.956 us; speedup vs baseline: 1.3152x; 1.0660x over previous
//
#include <hip/hip_runtime.h>
#include <hip/hip_bf16.h>
#include <hip/hip_fp16.h>
#include <math.h>

#define NPROJ 1024
#define NHEADS 4
#define NHID 256
#define NGRAPH 64

typedef _Float16 half8 __attribute__((ext_vector_type(8)));
typedef _Float16 half4v __attribute__((ext_vector_type(4)));
typedef float floatx4 __attribute__((ext_vector_type(4)));

#define GLD_LDS16(g, l)                                                        \
  __builtin_amdgcn_global_load_lds(                                            \
      (const __attribute__((address_space(1))) unsigned int*)(g),              \
      (__attribute__((address_space(3))) unsigned int*)(l), 16, 0, 0)

// ============================================================
// Single-product f16 MFMA GEMM:  C = A @ BT^T   (K fixed = 1024)
// A: M x 1024 f16 (hi of fp32).  B TRANSPOSED: Nc x 1024 f16 (hi of fp32).
// 128x128 tile, BK=64, 4 waves (2x2), wave 64x64, 16x16x32 MFMA.
// LDS = 2 x 16KB = 32KB -> 4 blocks/CU; grid 640 fits one residency round.
// Single-buffer overlap: frags->regs, barrier, STAGE(t+1) under MFMAs.
// XOR-swizzled LDS via pre-swizzled global source.
// XCD-chunked grid: each XCD owns mpad8 contiguous row-slabs, bx fastest.
// ============================================================
template<int ACT, int OUT>  // ACT: 0 none, 1 tanh; OUT: 0 f32, 2 f16
__global__ __launch_bounds__(256, 4) void gemm_mfma(
    const _Float16* __restrict__ A, const _Float16* __restrict__ BT,
    const float* __restrict__ bias, float* __restrict__ Cf,
    _Float16* __restrict__ Ch,
    int M, int Nc, int lgn, int mpad8)
{
  __shared__ __align__(16) _Float16 ldsA[128 * 64];
  __shared__ __align__(16) _Float16 ldsB[128 * 64];

  const int id  = blockIdx.x;
  const int xcd = id & 7;
  const int kk  = id >> 3;
  const int bx  = kk & ((1 << lgn) - 1);
  const int by  = xcd * mpad8 + (kk >> lgn);
  const int m0  = by * 128, n0 = bx * 128;
  if (m0 >= M) return;

  const int tid  = threadIdx.x;
  const int lane = tid & 63;
  const int wave = tid >> 6;
  const int wm = wave >> 1, wn = wave & 1;

  const int srow = tid >> 3;                              // + r*32
  const int kc8  = (((tid & 7) ^ ((tid >> 3) & 7)) << 3); // logical k elems
  const int wb16 = (tid & ~63) * 16;                      // wave-uniform base

  floatx4 acc[4][4] = {};

  const int l15 = lane & 15;
  const int swz = (l15 & 7) << 4;
  const int kbyte0 = (lane >> 4) * 16;

  auto STAGE = [&](int t) {
    const int k0 = t << 6;
#pragma unroll
    for (int r = 0; r < 4; ++r) {
      int rowA = m0 + r * 32 + srow;
      rowA = rowA < M ? rowA : (M - 1);
      GLD_LDS16(A + (size_t)rowA * 1024 + k0 + kc8,
                (char*)ldsA + r * 4096 + wb16);
      GLD_LDS16(BT + (size_t)(n0 + r * 32 + srow) * 1024 + k0 + kc8,
                (char*)ldsB + r * 4096 + wb16);
    }
  };

  STAGE(0);
  __syncthreads();

  for (int t = 0; t < 16; ++t) {
    const int koff0 = kbyte0 ^ swz;
    half8 a0[4], b0[4];
#pragma unroll
    for (int i = 0; i < 4; ++i)
      a0[i] = *(const half8*)((const char*)ldsA +
                              (wm * 64 + i * 16 + l15) * 128 + koff0);
#pragma unroll
    for (int j = 0; j < 4; ++j)
      b0[j] = *(const half8*)((const char*)ldsB +
                              (wn * 64 + j * 16 + l15) * 128 + koff0);
#pragma unroll
    for (int i = 0; i < 4; ++i)
#pragma unroll
      for (int j = 0; j < 4; ++j)
        acc[i][j] = __builtin_amdgcn_mfma_f32_16x16x32_f16(a0[i], b0[j],
                                                           acc[i][j], 0, 0, 0);

    const int koff1 = (64 + kbyte0) ^ swz;
    half8 a1[4], b1[4];
#pragma unroll
    for (int i = 0; i < 4; ++i)
      a1[i] = *(const half8*)((const char*)ldsA +
                              (wm * 64 + i * 16 + l15) * 128 + koff1);
#pragma unroll
    for (int j = 0; j < 4; ++j)
      b1[j] = *(const half8*)((const char*)ldsB +
                              (wn * 64 + j * 16 + l15) * 128 + koff1);
    __syncthreads();            // all LDS reads of tile t complete (regs held)
    if (t < 15) STAGE(t + 1);   // overwrite LDS under the MFMAs below

#pragma unroll
    for (int i = 0; i < 4; ++i)
#pragma unroll
      for (int j = 0; j < 4; ++j)
        acc[i][j] = __builtin_amdgcn_mfma_f32_16x16x32_f16(a1[i], b1[j],
                                                           acc[i][j], 0, 0, 0);

    if (t < 15) __syncthreads();  // vmcnt drain (mostly hidden by MFMAs)
  }

  // epilogue: C[row = (lane>>4)*4 + reg, col = lane&15] per 16x16 frag
  const int rbase = (lane >> 4) * 4;
#pragma unroll
  for (int j = 0; j < 4; ++j) {
    const int col = n0 + wn * 64 + j * 16 + l15;
    const float bv = bias ? bias[col] : 0.f;
#pragma unroll
    for (int i = 0; i < 4; ++i) {
      const int gm0 = m0 + wm * 64 + i * 16 + rbase;
#pragma unroll
      for (int r = 0; r < 4; ++r) {
        const int gm = gm0 + r;
        if (gm >= M) continue;
        float v = acc[i][j][r] + bv;
        if (ACT == 1) v = tanhf(v);
        if (OUT == 2) {
          Ch[(size_t)gm * Nc + col] = (_Float16)v;
        } else {
          Cf[(size_t)gm * Nc + col] = v;
        }
      }
    }
  }
}

// ============================================================
// converters
// ============================================================
__global__ void k_tof16(const float* __restrict__ in, _Float16* __restrict__ h,
                        int L8) {
  int i = blockIdx.x * 256 + threadIdx.x;
  if (i >= L8) return;
  const float4* p = (const float4*)(in + (size_t)i * 8);
  float4 v0 = p[0], v1 = p[1];
  float vv[8] = {v0.x, v0.y, v0.z, v0.w, v1.x, v1.y, v1.z, v1.w};
  half8 hv;
#pragma unroll
  for (int j = 0; j < 8; ++j) hv[j] = (_Float16)vv[j];
  *(half8*)(h + (size_t)i * 8) = hv;
}

// W (K x Nc) fp32 -> transposed (Nc x K) f16
__global__ __launch_bounds__(256) void k_transT(const float* __restrict__ in,
                                                _Float16* __restrict__ hT,
                                                int K, int Nc) {
  __shared__ float t[32][33];
  const int tx = threadIdx.x & 31, ty = threadIdx.x >> 5;
  const int c0 = blockIdx.x * 32, k0 = blockIdx.y * 32;
#pragma unroll
  for (int r = 0; r < 4; ++r)
    t[ty + 8 * r][tx] = in[(size_t)(k0 + ty + 8 * r) * Nc + c0 + tx];
  __syncthreads();
#pragma unroll
  for (int r = 0; r < 4; ++r) {
    float v = t[tx][ty + 8 * r];
    int oc = c0 + ty + 8 * r;
    hT[(size_t)oc * K + k0 + tx] = (_Float16)v;
  }
}

// ============================================================
// CSR-by-dst construction (recomputed every call; no caching)
// 3-level scan
// ============================================================
__global__ void k_init_counts(int* cnt, int n) {
  int i = blockIdx.x * 256 + threadIdx.x;
  if (i < n) cnt[i] = 1;  // self-loop pre-counted
}

__global__ void k_count(const int* __restrict__ dst, int* cnt, int e) {
  int i = blockIdx.x * 256 + threadIdx.x;
  if (i < e) atomicAdd(&cnt[dst[i]], 1);
}

__global__ __launch_bounds__(256) void k_scan1(int* __restrict__ cnt,
                                               int* __restrict__ bsum, int n) {
  __shared__ int wsum[4];
  const int b = blockIdx.x, t = threadIdx.x, i = b * 256 + t;
  const int x = (i < n) ? cnt[i] : 0;
  int v = x;
#pragma unroll
  for (int off = 1; off < 64; off <<= 1) {
    int u = __shfl_up(v, off);
    if ((t & 63) >= off) v += u;
  }
  if ((t & 63) == 63) wsum[t >> 6] = v;
  __syncthreads();
  int wo = 0;
#pragma unroll
  for (int w = 0; w < 4; ++w) wo += (w < (t >> 6)) ? wsum[w] : 0;
  const int incl = v + wo;
  if (i < n) cnt[i] = incl - x;
  if (t == 255) bsum[b] = incl;
}

__global__ void k_scan2(int* __restrict__ bsum, int nb) {
  const int t = threadIdx.x;
  const int x = (t < nb) ? bsum[t] : 0;
  int v = x;
#pragma unroll
  for (int off = 1; off < 64; off <<= 1) {
    int u = __shfl_up(v, off);
    if (t >= off) v += u;
  }
  if (t < nb) bsum[t] = v - x;
}

__global__ void k_scan3(const int* __restrict__ cnt, const int* __restrict__ bsum,
                        int* __restrict__ rowstart, int* __restrict__ cursor,
                        int n, int etot) {
  const int i = blockIdx.x * 256 + threadIdx.x;
  if (i < n) {
    const int v = cnt[i] + bsum[i >> 8];
    rowstart[i] = v;
    cursor[i] = v;
  }
  if (i == 0) rowstart[n] = etot;
}

__global__ void k_fill(const int* __restrict__ src, const int* __restrict__ dst,
                       int* cursor, int* __restrict__ col, int e) {
  int i = blockIdx.x * 256 + threadIdx.x;
  if (i < e) {
    int p = atomicAdd(&cursor[dst[i]], 1);
    col[p] = src[i];
  }
}

__global__ void k_fill_self(int* cursor, int* __restrict__ col, int n) {
  int i = blockIdx.x * 256 + threadIdx.x;
  if (i < n) {
    int p = atomicAdd(&cursor[i], 1);
    col[p] = i;
  }
}

// ============================================================
// per-node attention logits (f16 h): half8 loads, 2 heads/wave,
// 2 nodes per 256-thread block
// ============================================================
__global__ __launch_bounds__(256) void k_alpha(
    const _Float16* __restrict__ h, const float* __restrict__ a_src,
    const float* __restrict__ a_dst, float* __restrict__ as_out,
    float* __restrict__ ad_out, int N) {
  const int t = threadIdx.x;
  const int w = t >> 6, l = t & 63;
  const int node = blockIdx.x * 2 + (w >> 1);
  if (node >= N) return;
  const int head = (w & 1) * 2 + (l >> 5);
  const int cb = head * 256 + (l & 31) * 8;
  half8 v = *(const half8*)(h + (size_t)node * NPROJ + cb);
  float4 s0 = *(const float4*)(a_src + cb);
  float4 s1 = *(const float4*)(a_src + cb + 4);
  float4 d0 = *(const float4*)(a_dst + cb);
  float4 d1 = *(const float4*)(a_dst + cb + 4);
  float sv[8] = {s0.x, s0.y, s0.z, s0.w, s1.x, s1.y, s1.z, s1.w};
  float dv[8] = {d0.x, d0.y, d0.z, d0.w, d1.x, d1.y, d1.z, d1.w};
  float ss = 0.f, sd = 0.f;
#pragma unroll
  for (int j = 0; j < 8; ++j) {
    float f = (float)v[j];
    ss = fmaf(f, sv[j], ss);
    sd = fmaf(f, dv[j], sd);
  }
#pragma unroll
  for (int off = 1; off <= 16; off <<= 1) {
    ss += __shfl_xor(ss, off);
    sd += __shfl_xor(sd, off);
  }
  if ((l & 31) == 0) {
    as_out[node * 4 + head] = ss;
    ad_out[node * 4 + head] = sd;
  }
}

// ============================================================
// fused segment-softmax + aggregation + bias/ELU/residual/LayerNorm
// wave-per-head, in-wave shfl softmax, unroll-4 gather.
// NO max pass: scores bounded (|alpha| <~ 1), exp is overflow-safe and
// softmax is shift-invariant -> removes one col[]+as_ pass of three.
// First chunk (deg<=64 common case) caches edge idx + exp in registers.
// x is f16-only now (lo half dropped; GEMM A-path already used hi only).
// ============================================================
__device__ __forceinline__ float lrelu02(float x) {
  return x > 0.f ? x : 0.2f * x;
}

__global__ __launch_bounds__(256) void k_aggregate_ln(
    const _Float16* __restrict__ h, const float* __restrict__ as_,
    const float* __restrict__ ad_, const int* __restrict__ rowstart,
    const int* __restrict__ col, const float* __restrict__ bias,
    const float* __restrict__ gamma, const float* __restrict__ beta,
    _Float16* __restrict__ x) {
  __shared__ float sred[8];

  const int n = blockIdx.x, t = threadIdx.x;
  const int wv = t >> 6, l = t & 63;
  const int rs = rowstart[n], re = rowstart[n + 1];
  const float adn = ad_[n * 4 + wv];

  // single pass: sum of exp (no max); cache first-chunk edge in regs
  int s0 = 0;
  float e0 = 0.f;
  float sm = 0.f;
  {
    const int idx0 = rs + l;
    if (idx0 < re) {
      s0 = col[idx0];
      e0 = expf(lrelu02(as_[(size_t)s0 * 4 + wv] + adn));
      sm = e0;
    }
    for (int e = rs + 64 + l; e < re; e += 64)
      sm += expf(lrelu02(as_[(size_t)col[e] * 4 + wv] + adn));
  }
#pragma unroll
  for (int off = 32; off > 0; off >>= 1)
    sm += __shfl_xor(sm, off);
  const float Sinv = 1.f / (sm + 1e-16f);

  // gather; lane owns cols wv*256 + 4l .. +3 ; unroll-4 MLP
  const int cb = wv * 256 + 4 * l;
  float acc[4] = {0.f, 0.f, 0.f, 0.f};
  for (int c0 = rs; c0 < re; c0 += 64) {
    float w_l;
    int s_l;
    if (c0 == rs) {              // common case: from registers
      w_l = e0 * Sinv;
      s_l = s0;
    } else {                     // deg > 64 (rare): recompute
      const int idx = c0 + l;
      w_l = 0.f;
      s_l = 0;
      if (idx < re) {
        s_l = col[idx];
        w_l = expf(lrelu02(as_[(size_t)s_l * 4 + wv] + adn)) * Sinv;
      }
    }
    const int cnt = min(64, re - c0);
    int e = 0;
    for (; e + 3 < cnt; e += 4) {
      float w0 = __shfl(w_l, e + 0), w1 = __shfl(w_l, e + 1);
      float w2 = __shfl(w_l, e + 2), w3 = __shfl(w_l, e + 3);
      int q0 = __shfl(s_l, e + 0), q1 = __shfl(s_l, e + 1);
      int q2 = __shfl(s_l, e + 2), q3 = __shfl(s_l, e + 3);
      half4v h0 = *(const half4v*)(h + (size_t)q0 * NPROJ + cb);
      half4v h1 = *(const half4v*)(h + (size_t)q1 * NPROJ + cb);
      half4v h2 = *(const half4v*)(h + (size_t)q2 * NPROJ + cb);
      half4v h3 = *(const half4v*)(h + (size_t)q3 * NPROJ + cb);
#pragma unroll
      for (int j = 0; j < 4; ++j) {
        acc[j] = fmaf(w0, (float)h0[j], acc[j]);
        acc[j] = fmaf(w1, (float)h1[j], acc[j]);
        acc[j] = fmaf(w2, (float)h2[j], acc[j]);
        acc[j] = fmaf(w3, (float)h3[j], acc[j]);
      }
    }
    for (; e < cnt; ++e) {
      const float w = __shfl(w_l, e);
      const int s = __shfl(s_l, e);
      half4v hv = *(const half4v*)(h + (size_t)s * NPROJ + cb);
      acc[0] = fmaf(w, (float)hv[0], acc[0]);
      acc[1] = fmaf(w, (float)hv[1], acc[1]);
      acc[2] = fmaf(w, (float)hv[2], acc[2]);
      acc[3] = fmaf(w, (float)hv[3], acc[3]);
    }
  }

  // epilogue: bias, ELU, residual (f16 x); LayerNorm stats
  const size_t base = (size_t)n * NPROJ + cb;
  float4 b4 = *(const float4*)(bias + cb);
  float bb[4] = {b4.x, b4.y, b4.z, b4.w};
  half4v xv = *(const half4v*)(x + base);
  float v[4];
  float sum = 0.f, sumsq = 0.f;
#pragma unroll
  for (int j = 0; j < 4; ++j) {
    float u = acc[j] + bb[j];
    u = u > 0.f ? u : expm1f(u);
    u += (float)xv[j];
    v[j] = u;
    sum += u;
    sumsq += u * u;
  }
#pragma unroll
  for (int off = 32; off > 0; off >>= 1) {
    sum += __shfl_xor(sum, off);
    sumsq += __shfl_xor(sumsq, off);
  }
  if (l == 0) {
    sred[wv] = sum;
    sred[4 + wv] = sumsq;
  }
  __syncthreads();
  const float tsum = sred[0] + sred[1] + sred[2] + sred[3];
  const float tssq = sred[4] + sred[5] + sred[6] + sred[7];
  const float mu = tsum * (1.f / 1024.f);
  const float var = tssq * (1.f / 1024.f) - mu * mu;
  const float rstd = rsqrtf(var + 1e-5f);

  float4 g4 = *(const float4*)(gamma + cb);
  float4 e4 = *(const float4*)(beta + cb);
  float gg[4] = {g4.x, g4.y, g4.z, g4.w};
  float ee[4] = {e4.x, e4.y, e4.z, e4.w};
  half4v ox;
#pragma unroll
  for (int j = 0; j < 4; ++j)
    ox[j] = (_Float16)((v[j] - mu) * rstd * gg[j] + ee[j]);
  *(half4v*)(x + base) = ox;
}

// ============================================================
// pooling + classifier
// ============================================================
__global__ void k_scores(const float* __restrict__ tb,
                         const float* __restrict__ W2,
                         const float* __restrict__ b2,
                         float* __restrict__ scores, int N) {
  int n = blockIdx.x, lane = threadIdx.x;
  float s = 0.f;
  for (int k = lane; k < 512; k += 64) s = fmaf(tb[(size_t)n * 512 + k], W2[k], s);
  for (int off = 32; off > 0; off >>= 1) s += __shfl_down(s, off);
  if (lane == 0) scores[n] = s + b2[0];
}

__global__ void k_grange_init(int* gstart, int* gend, int N) {
  int g = threadIdx.x;
  if (g < NGRAPH) { gstart[g] = N; gend[g] = 0; }
}

__global__ void k_grange_mark(const int* __restrict__ batch, int* gstart,
                              int* gend, int N) {
  int n = blockIdx.x * 256 + threadIdx.x;
  if (n >= N) return;
  int b = batch[n];
  if (n == 0 || batch[n - 1] != b) gstart[b] = n;
  if (n == N - 1 || batch[n + 1] != b) gend[b] = n + 1;
}

// per-graph softmax over scores -> normalized weights (in place)
__global__ __launch_bounds__(256) void k_poolw(
    float* __restrict__ scores, const int* __restrict__ gstart,
    const int* __restrict__ gend) {
  __shared__ float red[256];
  __shared__ float m_s, s_s;
  int g = blockIdx.x, t = threadIdx.x;
  int rs = gstart[g], re = gend[g];

  float mx = -1e30f;
  for (int i = rs + t; i < re; i += 256) mx = fmaxf(mx, scores[i]);
  red[t] = mx;
  __syncthreads();
  for (int s = 128; s > 0; s >>= 1) {
    if (t < s) red[t] = fmaxf(red[t], red[t + s]);
    __syncthreads();
  }
  if (t == 0) m_s = red[0];
  __syncthreads();
  float m = m_s;

  float sm = 0.f;
  for (int i = rs + t; i < re; i += 256) sm += expf(scores[i] - m);
  red[t] = sm;
  __syncthreads();
  for (int s = 128; s > 0; s >>= 1) {
    if (t < s) red[t] += red[t + s];
    __syncthreads();
  }
  if (t == 0) s_s = red[0] + 1e-16f;
  __syncthreads();
  float sinv = 1.f / s_s;

  for (int i = rs + t; i < re; i += 256)
    scores[i] = expf(scores[i] - m) * sinv;
}

// weighted segment sum: grid (NGRAPH, 4); block (g,q) covers cols
// q*256..q*256+255; 4 waves node-stride-4, lane owns 4 cols (8B loads)
__global__ __launch_bounds__(256) void k_pool2(
    const float* __restrict__ w, const _Float16* __restrict__ x,
    const int* __restrict__ gstart, const int* __restrict__ gend,
    float* __restrict__ pooled) {
  __shared__ float red[3][64][4];
  const int g = blockIdx.x, q = blockIdx.y;
  const int t = threadIdx.x, wv = t >> 6, l = t & 63;
  const int rs = gstart[g], re = gend[g];
  const int cb = q * 256 + 4 * l;

  float acc[4] = {0.f, 0.f, 0.f, 0.f};
  for (int n = rs + wv; n < re; n += 4) {
    const float wn = w[n];
    half4v hv = *(const half4v*)(x + (size_t)n * NPROJ + cb);
#pragma unroll
    for (int j = 0; j < 4; ++j)
      acc[j] = fmaf(wn, (float)hv[j], acc[j]);
  }
  if (wv) {
#pragma unroll
    for (int j = 0; j < 4; ++j) red[wv - 1][l][j] = acc[j];
  }
  __syncthreads();
  if (wv == 0) {
#pragma unroll
    for (int k = 0; k < 3; ++k)
#pragma unroll
      for (int j = 0; j < 4; ++j) acc[j] += red[k][l][j];
    float4 o = make_float4(acc[0], acc[1], acc[2], acc[3]);
    *(float4*)(pooled + (size_t)g * NPROJ + cb) = o;
  }
}

__global__ __launch_bounds__(256) void k_cls1(const float* __restrict__ pooled,
                                              const float* __restrict__ W1,
                                              const float* __restrict__ b1,
                                              float* __restrict__ hid) {
  __shared__ float p[1024];
  int g = blockIdx.y;
  int colc = blockIdx.x * 256 + threadIdx.x;
  for (int k = threadIdx.x; k < 1024; k += 256) p[k] = pooled[(size_t)g * 1024 + k];
  __syncthreads();
  float s = 0.f;
  for (int k = 0; k < 1024; ++k) s = fmaf(p[k], W1[(size_t)k * 512 + colc], s);
  s += b1[colc];
  s = 0.5f * s * (1.f + erff(s * 0.70710678118654752f));
  hid[(size_t)g * 512 + colc] = s;
}

__global__ void k_cls2(const float* __restrict__ hid,
                       const float* __restrict__ W2,
                       const float* __restrict__ b2, float* __restrict__ out) {
  int o = blockIdx.x, g = blockIdx.y, lane = threadIdx.x;
  float s = 0.f;
  for (int k = lane; k < 512; k += 64) s = fmaf(hid[(size_t)g * 512 + k], W2[k * 14 + o], s);
  for (int off = 32; off > 0; off >>= 1) s += __shfl_down(s, off);
  if (lane == 0) out[g * 14 + o] = s + b2[o];
}

// ============================================================
extern "C" void kernel_launch(void* const* d_in, const int* in_sizes, int n_in,
                              void* d_out, int out_size, void* d_ws, size_t ws_size,
                              hipStream_t stream) {
  const float* x_in   = (const float*)d_in[0];
  const int*   eidx   = (const int*)d_in[1];
  const int*   batch  = (const int*)d_in[2];
  const float* proj_W = (const float*)d_in[3];
  const float* proj_b = (const float*)d_in[4];
  const float* gat_W  = (const float*)d_in[5];
  const float* a_src  = (const float*)d_in[6];
  const float* a_dst  = (const float*)d_in[7];
  const float* gat_b  = (const float*)d_in[8];
  const float* gamma  = (const float*)d_in[9];
  const float* beta   = (const float*)d_in[10];
  const float* pW1    = (const float*)d_in[11];
  const float* pb1    = (const float*)d_in[12];
  const float* pW2    = (const float*)d_in[13];
  const float* pb2    = (const float*)d_in[14];
  const float* cW1    = (const float*)d_in[15];
  const float* cb1    = (const float*)d_in[16];
  const float* cW2    = (const float*)d_in[17];
  const float* cb2    = (const float*)d_in[18];
  float* out = (float*)d_out;

  const int N = in_sizes[0] / NPROJ;  // 10000
  const int E = in_sizes[1] / 2;      // 160000
  const int Etot = E + N;
  const int NB = (N + 255) / 256;     // 40 scan blocks

  char* ws = (char*)d_ws;
  size_t off = 0;
  auto alloc = [&](size_t bytes) -> void* {
    void* p = ws + off;
    off = (off + bytes + 255) & ~(size_t)255;
    return p;
  };
  _Float16* xh   = (_Float16*)alloc((size_t)N * NPROJ * 2);
  _Float16* hf   = (_Float16*)alloc((size_t)N * NPROJ * 2);   // f16 h
  float*    hb   = (float*)alloc((size_t)N * NPROJ * 4);      // in-f16 / tb
  _Float16* pjh  = (_Float16*)alloc((size_t)NPROJ * NPROJ * 2);
  _Float16* gwh  = (_Float16*)alloc((size_t)3 * NPROJ * NPROJ * 2);
  _Float16* pwh  = (_Float16*)alloc((size_t)512 * NPROJ * 2);
  float* asb     = (float*)alloc((size_t)N * 4 * 4);
  float* adb     = (float*)alloc((size_t)N * 4 * 4);
  int*   cnt     = (int*)alloc((size_t)N * 4);
  int*   bsum    = (int*)alloc(64 * 4);
  int*   rowst   = (int*)alloc((size_t)(N + 1) * 4);
  int*   cursor  = (int*)alloc((size_t)N * 4);
  int*   ccol    = (int*)alloc((size_t)Etot * 4);
  float* scores  = (float*)alloc((size_t)N * 4);
  int*   gstart  = (int*)alloc(NGRAPH * 4);
  int*   gend    = (int*)alloc(NGRAPH * 4);
  float* pooled  = (float*)alloc((size_t)NGRAPH * NPROJ * 4);
  float* hid     = (float*)alloc((size_t)NGRAPH * 512 * 4);

  const int* esrc = eidx;
  const int* edst = eidx + E;

  // ---- CSR by dst (3-level scan) ----
  k_init_counts<<<NB, 256, 0, stream>>>(cnt, N);
  k_count<<<(E + 255) / 256, 256, 0, stream>>>(edst, cnt, E);
  k_scan1<<<NB, 256, 0, stream>>>(cnt, bsum, N);
  k_scan2<<<1, 64, 0, stream>>>(bsum, NB);
  k_scan3<<<NB, 256, 0, stream>>>(cnt, bsum, rowst, cursor, N, Etot);
  k_fill<<<(E + 255) / 256, 256, 0, stream>>>(esrc, edst, cursor, ccol, E);
  k_fill_self<<<NB, 256, 0, stream>>>(cursor, ccol, N);

  // ---- weight transposes (f16 hi) ----
  k_transT<<<dim3(32, 32), 256, 0, stream>>>(proj_W, pjh, NPROJ, NPROJ);
  for (int i = 0; i < 3; ++i)
    k_transT<<<dim3(32, 32), 256, 0, stream>>>(gat_W + (size_t)i * NPROJ * NPROJ,
                                               gwh + (size_t)i * NPROJ * NPROJ,
                                               NPROJ, NPROJ);
  k_transT<<<dim3(16, 32), 256, 0, stream>>>(pW1, pwh, NPROJ, 512);

  // ---- input f16 (scratch inside hb) + projection ----
  _Float16* inh = (_Float16*)hb;
  k_tof16<<<((N * NPROJ / 8) + 255) / 256, 256, 0, stream>>>(x_in, inh,
                                                             N * NPROJ / 8);
  const int MB = (N + 127) / 128;       // 79
  const int mpad8 = (MB + 7) / 8;       // 10
  const dim3 grid8(8 * mpad8 * 8);      // Nc=1024: lgn=3
  const dim3 grid4(4 * mpad8 * 8);      // Nc=512:  lgn=2
  gemm_mfma<0, 2><<<grid8, 256, 0, stream>>>(
      inh, pjh, proj_b, nullptr, xh, N, NPROJ, 3, mpad8);

  // ---- 3 GAT layers ----
  for (int i = 0; i < 3; ++i) {
    gemm_mfma<0, 2><<<grid8, 256, 0, stream>>>(
        xh, gwh + (size_t)i * NPROJ * NPROJ,
        nullptr, nullptr, hf, N, NPROJ, 3, mpad8);
    k_alpha<<<(N + 1) / 2, 256, 0, stream>>>(hf, a_src + i * NPROJ,
                                             a_dst + i * NPROJ, asb, adb, N);
    k_aggregate_ln<<<N, 256, 0, stream>>>(hf, asb, adb, rowst, ccol,
                                          gat_b + i * NPROJ, gamma + i * NPROJ,
                                          beta + i * NPROJ, xh);
  }

  // ---- attention pooling ----
  float* tb = hb;  // N x 512 f32
  gemm_mfma<1, 0><<<grid4, 256, 0, stream>>>(
      xh, pwh, pb1, tb, nullptr, N, 512, 2, mpad8);
  k_scores<<<N, 64, 0, stream>>>(tb, pW2, pb2, scores, N);
  k_grange_init<<<1, 64, 0, stream>>>(gstart, gend, N);
  k_grange_mark<<<NB, 256, 0, stream>>>(batch, gstart, gend, N);
  k_poolw<<<NGRAPH, 256, 0, stream>>>(scores, gstart, gend);
  k_pool2<<<dim3(NGRAPH, 4), 256, 0, stream>>>(scores, xh, gstart, gend,
                                               pooled);

  // ---- classifier ----
  k_cls1<<<dim3(2, NGRAPH), 256, 0, stream>>>(pooled, cW1, cb1, hid);
  k_cls2<<<dim3(14, NGRAPH), 64, 0, stream>>>(hid, cW2, cb2, out);
}

// Round 15
// 436.345 us; speedup vs baseline: 1.3652x; 1.0381x over previous
//
#include <hip/hip_runtime.h>
#include <hip/hip_bf16.h>
#include <hip/hip_fp16.h>
#include <math.h>

#define NPROJ 1024
#define NHEADS 4
#define NHID 256
#define NGRAPH 64

typedef _Float16 half8 __attribute__((ext_vector_type(8)));
typedef _Float16 half4v __attribute__((ext_vector_type(4)));
typedef float floatx4 __attribute__((ext_vector_type(4)));

#define GLD_LDS16(g, l)                                                        \
  __builtin_amdgcn_global_load_lds(                                            \
      (const __attribute__((address_space(1))) unsigned int*)(g),              \
      (__attribute__((address_space(3))) unsigned int*)(l), 16, 0, 0)

// ============================================================
// Single-product f16 MFMA GEMM:  C = A @ BT^T   (K fixed = 1024)
// A: M x 1024 f16.  B TRANSPOSED: Nc x 1024 f16.
// Tile BM x 128 (BM=128 or 64), BK=64, 4 waves (2x2), wave (BM/2)x64.
// BM=128: LDS 32KB, 4 blocks/CU.  BM=64: LDS 24KB, finer grid for small-Nc
// dispatches (pool GEMM was 1.25 blocks/CU at BM=128 -> latency-bound).
// Single-buffer overlap: frags->regs, barrier, STAGE(t+1) under MFMAs.
// XOR-swizzled LDS via pre-swizzled global source.
// XCD-chunked grid: each XCD owns mpad8 contiguous row-slabs, bx fastest.
// ============================================================
template<int ACT, int OUT, int BM>  // ACT: 0 none,1 tanh; OUT: 0 f32,2 f16
__global__ __launch_bounds__(256, 4) void gemm_mfma(
    const _Float16* __restrict__ A, const _Float16* __restrict__ BT,
    const float* __restrict__ bias, float* __restrict__ Cf,
    _Float16* __restrict__ Ch,
    int M, int Nc, int lgn, int mpad8)
{
  constexpr int WMT = BM / 2;    // wave m-tile
  constexpr int MFR = WMT / 16;  // m fragments per wave
  constexpr int AR  = BM / 32;   // A staging rounds

  __shared__ __align__(16) _Float16 ldsA[BM * 64];
  __shared__ __align__(16) _Float16 ldsB[128 * 64];

  const int id  = blockIdx.x;
  const int xcd = id & 7;
  const int kk  = id >> 3;
  const int bx  = kk & ((1 << lgn) - 1);
  const int by  = xcd * mpad8 + (kk >> lgn);
  const int m0  = by * BM, n0 = bx * 128;
  if (m0 >= M) return;

  const int tid  = threadIdx.x;
  const int lane = tid & 63;
  const int wave = tid >> 6;
  const int wm = wave >> 1, wn = wave & 1;

  const int srow = tid >> 3;                              // + r*32
  const int kc8  = (((tid & 7) ^ ((tid >> 3) & 7)) << 3); // logical k elems
  const int wb16 = (tid & ~63) * 16;                      // wave-uniform base

  floatx4 acc[MFR][4] = {};

  const int l15 = lane & 15;
  const int swz = (l15 & 7) << 4;
  const int kbyte0 = (lane >> 4) * 16;

  auto STAGE = [&](int t) {
    const int k0 = t << 6;
#pragma unroll
    for (int r = 0; r < AR; ++r) {
      int rowA = m0 + r * 32 + srow;
      rowA = rowA < M ? rowA : (M - 1);
      GLD_LDS16(A + (size_t)rowA * 1024 + k0 + kc8,
                (char*)ldsA + r * 4096 + wb16);
    }
#pragma unroll
    for (int r = 0; r < 4; ++r)
      GLD_LDS16(BT + (size_t)(n0 + r * 32 + srow) * 1024 + k0 + kc8,
                (char*)ldsB + r * 4096 + wb16);
  };

  STAGE(0);
  __syncthreads();

  for (int t = 0; t < 16; ++t) {
    const int koff0 = kbyte0 ^ swz;
    half8 a0[MFR], b0[4];
#pragma unroll
    for (int i = 0; i < MFR; ++i)
      a0[i] = *(const half8*)((const char*)ldsA +
                              (wm * WMT + i * 16 + l15) * 128 + koff0);
#pragma unroll
    for (int j = 0; j < 4; ++j)
      b0[j] = *(const half8*)((const char*)ldsB +
                              (wn * 64 + j * 16 + l15) * 128 + koff0);
#pragma unroll
    for (int i = 0; i < MFR; ++i)
#pragma unroll
      for (int j = 0; j < 4; ++j)
        acc[i][j] = __builtin_amdgcn_mfma_f32_16x16x32_f16(a0[i], b0[j],
                                                           acc[i][j], 0, 0, 0);

    const int koff1 = (64 + kbyte0) ^ swz;
    half8 a1[MFR], b1[4];
#pragma unroll
    for (int i = 0; i < MFR; ++i)
      a1[i] = *(const half8*)((const char*)ldsA +
                              (wm * WMT + i * 16 + l15) * 128 + koff1);
#pragma unroll
    for (int j = 0; j < 4; ++j)
      b1[j] = *(const half8*)((const char*)ldsB +
                              (wn * 64 + j * 16 + l15) * 128 + koff1);
    __syncthreads();            // all LDS reads of tile t complete (regs held)
    if (t < 15) STAGE(t + 1);   // overwrite LDS under the MFMAs below

#pragma unroll
    for (int i = 0; i < MFR; ++i)
#pragma unroll
      for (int j = 0; j < 4; ++j)
        acc[i][j] = __builtin_amdgcn_mfma_f32_16x16x32_f16(a1[i], b1[j],
                                                           acc[i][j], 0, 0, 0);

    if (t < 15) __syncthreads();  // vmcnt drain (mostly hidden by MFMAs)
  }

  // epilogue: C[row = (lane>>4)*4 + reg, col = lane&15] per 16x16 frag
  const int rbase = (lane >> 4) * 4;
#pragma unroll
  for (int j = 0; j < 4; ++j) {
    const int col = n0 + wn * 64 + j * 16 + l15;
    const float bv = bias ? bias[col] : 0.f;
#pragma unroll
    for (int i = 0; i < MFR; ++i) {
      const int gm0 = m0 + wm * WMT + i * 16 + rbase;
#pragma unroll
      for (int r = 0; r < 4; ++r) {
        const int gm = gm0 + r;
        if (gm >= M) continue;
        float v = acc[i][j][r] + bv;
        if (ACT == 1) v = tanhf(v);
        if (OUT == 2) {
          Ch[(size_t)gm * Nc + col] = (_Float16)v;
        } else {
          Cf[(size_t)gm * Nc + col] = v;
        }
      }
    }
  }
}

// ============================================================
// converters
// ============================================================
__global__ void k_tof16(const float* __restrict__ in, _Float16* __restrict__ h,
                        int L8) {
  int i = blockIdx.x * 256 + threadIdx.x;
  if (i >= L8) return;
  const float4* p = (const float4*)(in + (size_t)i * 8);
  float4 v0 = p[0], v1 = p[1];
  float vv[8] = {v0.x, v0.y, v0.z, v0.w, v1.x, v1.y, v1.z, v1.w};
  half8 hv;
#pragma unroll
  for (int j = 0; j < 8; ++j) hv[j] = (_Float16)vv[j];
  *(half8*)(h + (size_t)i * 8) = hv;
}

// W (K x Nc) fp32 -> transposed (Nc x K) f16
__global__ __launch_bounds__(256) void k_transT(const float* __restrict__ in,
                                                _Float16* __restrict__ hT,
                                                int K, int Nc) {
  __shared__ float t[32][33];
  const int tx = threadIdx.x & 31, ty = threadIdx.x >> 5;
  const int c0 = blockIdx.x * 32, k0 = blockIdx.y * 32;
#pragma unroll
  for (int r = 0; r < 4; ++r)
    t[ty + 8 * r][tx] = in[(size_t)(k0 + ty + 8 * r) * Nc + c0 + tx];
  __syncthreads();
#pragma unroll
  for (int r = 0; r < 4; ++r) {
    float v = t[tx][ty + 8 * r];
    int oc = c0 + ty + 8 * r;
    hT[(size_t)oc * K + k0 + tx] = (_Float16)v;
  }
}

// ============================================================
// CSR-by-dst construction (recomputed every call; no caching)
// 3-level scan
// ============================================================
__global__ void k_init_counts(int* cnt, int n) {
  int i = blockIdx.x * 256 + threadIdx.x;
  if (i < n) cnt[i] = 1;  // self-loop pre-counted
}

__global__ void k_count(const int* __restrict__ dst, int* cnt, int e) {
  int i = blockIdx.x * 256 + threadIdx.x;
  if (i < e) atomicAdd(&cnt[dst[i]], 1);
}

__global__ __launch_bounds__(256) void k_scan1(int* __restrict__ cnt,
                                               int* __restrict__ bsum, int n) {
  __shared__ int wsum[4];
  const int b = blockIdx.x, t = threadIdx.x, i = b * 256 + t;
  const int x = (i < n) ? cnt[i] : 0;
  int v = x;
#pragma unroll
  for (int off = 1; off < 64; off <<= 1) {
    int u = __shfl_up(v, off);
    if ((t & 63) >= off) v += u;
  }
  if ((t & 63) == 63) wsum[t >> 6] = v;
  __syncthreads();
  int wo = 0;
#pragma unroll
  for (int w = 0; w < 4; ++w) wo += (w < (t >> 6)) ? wsum[w] : 0;
  const int incl = v + wo;
  if (i < n) cnt[i] = incl - x;
  if (t == 255) bsum[b] = incl;
}

__global__ void k_scan2(int* __restrict__ bsum, int nb) {
  const int t = threadIdx.x;
  const int x = (t < nb) ? bsum[t] : 0;
  int v = x;
#pragma unroll
  for (int off = 1; off < 64; off <<= 1) {
    int u = __shfl_up(v, off);
    if (t >= off) v += u;
  }
  if (t < nb) bsum[t] = v - x;
}

__global__ void k_scan3(const int* __restrict__ cnt, const int* __restrict__ bsum,
                        int* __restrict__ rowstart, int* __restrict__ cursor,
                        int n, int etot) {
  const int i = blockIdx.x * 256 + threadIdx.x;
  if (i < n) {
    const int v = cnt[i] + bsum[i >> 8];
    rowstart[i] = v;
    cursor[i] = v;
  }
  if (i == 0) rowstart[n] = etot;
}

__global__ void k_fill(const int* __restrict__ src, const int* __restrict__ dst,
                       int* cursor, int* __restrict__ col, int e) {
  int i = blockIdx.x * 256 + threadIdx.x;
  if (i < e) {
    int p = atomicAdd(&cursor[dst[i]], 1);
    col[p] = src[i];
  }
}

__global__ void k_fill_self(int* cursor, int* __restrict__ col, int n) {
  int i = blockIdx.x * 256 + threadIdx.x;
  if (i < n) {
    int p = atomicAdd(&cursor[i], 1);
    col[p] = i;
  }
}

// ============================================================
// per-node attention logits (f16 h): half8 loads, 2 heads/wave,
// 2 nodes per 256-thread block
// ============================================================
__global__ __launch_bounds__(256) void k_alpha(
    const _Float16* __restrict__ h, const float* __restrict__ a_src,
    const float* __restrict__ a_dst, float* __restrict__ as_out,
    float* __restrict__ ad_out, int N) {
  const int t = threadIdx.x;
  const int w = t >> 6, l = t & 63;
  const int node = blockIdx.x * 2 + (w >> 1);
  if (node >= N) return;
  const int head = (w & 1) * 2 + (l >> 5);
  const int cb = head * 256 + (l & 31) * 8;
  half8 v = *(const half8*)(h + (size_t)node * NPROJ + cb);
  float4 s0 = *(const float4*)(a_src + cb);
  float4 s1 = *(const float4*)(a_src + cb + 4);
  float4 d0 = *(const float4*)(a_dst + cb);
  float4 d1 = *(const float4*)(a_dst + cb + 4);
  float sv[8] = {s0.x, s0.y, s0.z, s0.w, s1.x, s1.y, s1.z, s1.w};
  float dv[8] = {d0.x, d0.y, d0.z, d0.w, d1.x, d1.y, d1.z, d1.w};
  float ss = 0.f, sd = 0.f;
#pragma unroll
  for (int j = 0; j < 8; ++j) {
    float f = (float)v[j];
    ss = fmaf(f, sv[j], ss);
    sd = fmaf(f, dv[j], sd);
  }
#pragma unroll
  for (int off = 1; off <= 16; off <<= 1) {
    ss += __shfl_xor(ss, off);
    sd += __shfl_xor(sd, off);
  }
  if ((l & 31) == 0) {
    as_out[node * 4 + head] = ss;
    ad_out[node * 4 + head] = sd;
  }
}

// ============================================================
// fused segment-softmax + aggregation + bias/ELU/residual/LayerNorm
// wave-per-head, in-wave shfl softmax (no max pass -- scores bounded),
// unroll-4 gather, first-chunk cached in registers, f16 x.
// ============================================================
__device__ __forceinline__ float lrelu02(float x) {
  return x > 0.f ? x : 0.2f * x;
}

__global__ __launch_bounds__(256) void k_aggregate_ln(
    const _Float16* __restrict__ h, const float* __restrict__ as_,
    const float* __restrict__ ad_, const int* __restrict__ rowstart,
    const int* __restrict__ col, const float* __restrict__ bias,
    const float* __restrict__ gamma, const float* __restrict__ beta,
    _Float16* __restrict__ x) {
  __shared__ float sred[8];

  const int n = blockIdx.x, t = threadIdx.x;
  const int wv = t >> 6, l = t & 63;
  const int rs = rowstart[n], re = rowstart[n + 1];
  const float adn = ad_[n * 4 + wv];

  // single pass: sum of exp (no max); cache first-chunk edge in regs
  int s0 = 0;
  float e0 = 0.f;
  float sm = 0.f;
  {
    const int idx0 = rs + l;
    if (idx0 < re) {
      s0 = col[idx0];
      e0 = expf(lrelu02(as_[(size_t)s0 * 4 + wv] + adn));
      sm = e0;
    }
    for (int e = rs + 64 + l; e < re; e += 64)
      sm += expf(lrelu02(as_[(size_t)col[e] * 4 + wv] + adn));
  }
#pragma unroll
  for (int off = 32; off > 0; off >>= 1)
    sm += __shfl_xor(sm, off);
  const float Sinv = 1.f / (sm + 1e-16f);

  // gather; lane owns cols wv*256 + 4l .. +3 ; unroll-4 MLP
  const int cb = wv * 256 + 4 * l;
  float acc[4] = {0.f, 0.f, 0.f, 0.f};
  for (int c0 = rs; c0 < re; c0 += 64) {
    float w_l;
    int s_l;
    if (c0 == rs) {
      w_l = e0 * Sinv;
      s_l = s0;
    } else {
      const int idx = c0 + l;
      w_l = 0.f;
      s_l = 0;
      if (idx < re) {
        s_l = col[idx];
        w_l = expf(lrelu02(as_[(size_t)s_l * 4 + wv] + adn)) * Sinv;
      }
    }
    const int cnt = min(64, re - c0);
    int e = 0;
    for (; e + 3 < cnt; e += 4) {
      float w0 = __shfl(w_l, e + 0), w1 = __shfl(w_l, e + 1);
      float w2 = __shfl(w_l, e + 2), w3 = __shfl(w_l, e + 3);
      int q0 = __shfl(s_l, e + 0), q1 = __shfl(s_l, e + 1);
      int q2 = __shfl(s_l, e + 2), q3 = __shfl(s_l, e + 3);
      half4v h0 = *(const half4v*)(h + (size_t)q0 * NPROJ + cb);
      half4v h1 = *(const half4v*)(h + (size_t)q1 * NPROJ + cb);
      half4v h2 = *(const half4v*)(h + (size_t)q2 * NPROJ + cb);
      half4v h3 = *(const half4v*)(h + (size_t)q3 * NPROJ + cb);
#pragma unroll
      for (int j = 0; j < 4; ++j) {
        acc[j] = fmaf(w0, (float)h0[j], acc[j]);
        acc[j] = fmaf(w1, (float)h1[j], acc[j]);
        acc[j] = fmaf(w2, (float)h2[j], acc[j]);
        acc[j] = fmaf(w3, (float)h3[j], acc[j]);
      }
    }
    for (; e < cnt; ++e) {
      const float w = __shfl(w_l, e);
      const int s = __shfl(s_l, e);
      half4v hv = *(const half4v*)(h + (size_t)s * NPROJ + cb);
      acc[0] = fmaf(w, (float)hv[0], acc[0]);
      acc[1] = fmaf(w, (float)hv[1], acc[1]);
      acc[2] = fmaf(w, (float)hv[2], acc[2]);
      acc[3] = fmaf(w, (float)hv[3], acc[3]);
    }
  }

  // epilogue: bias, ELU, residual (f16 x); LayerNorm stats
  const size_t base = (size_t)n * NPROJ + cb;
  float4 b4 = *(const float4*)(bias + cb);
  float bb[4] = {b4.x, b4.y, b4.z, b4.w};
  half4v xv = *(const half4v*)(x + base);
  float v[4];
  float sum = 0.f, sumsq = 0.f;
#pragma unroll
  for (int j = 0; j < 4; ++j) {
    float u = acc[j] + bb[j];
    u = u > 0.f ? u : expm1f(u);
    u += (float)xv[j];
    v[j] = u;
    sum += u;
    sumsq += u * u;
  }
#pragma unroll
  for (int off = 32; off > 0; off >>= 1) {
    sum += __shfl_xor(sum, off);
    sumsq += __shfl_xor(sumsq, off);
  }
  if (l == 0) {
    sred[wv] = sum;
    sred[4 + wv] = sumsq;
  }
  __syncthreads();
  const float tsum = sred[0] + sred[1] + sred[2] + sred[3];
  const float tssq = sred[4] + sred[5] + sred[6] + sred[7];
  const float mu = tsum * (1.f / 1024.f);
  const float var = tssq * (1.f / 1024.f) - mu * mu;
  const float rstd = rsqrtf(var + 1e-5f);

  float4 g4 = *(const float4*)(gamma + cb);
  float4 e4 = *(const float4*)(beta + cb);
  float gg[4] = {g4.x, g4.y, g4.z, g4.w};
  float ee[4] = {e4.x, e4.y, e4.z, e4.w};
  half4v ox;
#pragma unroll
  for (int j = 0; j < 4; ++j)
    ox[j] = (_Float16)((v[j] - mu) * rstd * gg[j] + ee[j]);
  *(half4v*)(x + base) = ox;
}

// ============================================================
// pooling + classifier
// ============================================================
__global__ void k_scores(const float* __restrict__ tb,
                         const float* __restrict__ W2,
                         const float* __restrict__ b2,
                         float* __restrict__ scores, int N) {
  int n = blockIdx.x, lane = threadIdx.x;
  float s = 0.f;
  for (int k = lane; k < 512; k += 64) s = fmaf(tb[(size_t)n * 512 + k], W2[k], s);
  for (int off = 32; off > 0; off >>= 1) s += __shfl_down(s, off);
  if (lane == 0) scores[n] = s + b2[0];
}

__global__ void k_grange_init(int* gstart, int* gend, int N) {
  int g = threadIdx.x;
  if (g < NGRAPH) { gstart[g] = N; gend[g] = 0; }
}

__global__ void k_grange_mark(const int* __restrict__ batch, int* gstart,
                              int* gend, int N) {
  int n = blockIdx.x * 256 + threadIdx.x;
  if (n >= N) return;
  int b = batch[n];
  if (n == 0 || batch[n - 1] != b) gstart[b] = n;
  if (n == N - 1 || batch[n + 1] != b) gend[b] = n + 1;
}

// per-graph softmax over scores -> normalized weights (in place)
__global__ __launch_bounds__(256) void k_poolw(
    float* __restrict__ scores, const int* __restrict__ gstart,
    const int* __restrict__ gend) {
  __shared__ float red[256];
  __shared__ float m_s, s_s;
  int g = blockIdx.x, t = threadIdx.x;
  int rs = gstart[g], re = gend[g];

  float mx = -1e30f;
  for (int i = rs + t; i < re; i += 256) mx = fmaxf(mx, scores[i]);
  red[t] = mx;
  __syncthreads();
  for (int s = 128; s > 0; s >>= 1) {
    if (t < s) red[t] = fmaxf(red[t], red[t + s]);
    __syncthreads();
  }
  if (t == 0) m_s = red[0];
  __syncthreads();
  float m = m_s;

  float sm = 0.f;
  for (int i = rs + t; i < re; i += 256) sm += expf(scores[i] - m);
  red[t] = sm;
  __syncthreads();
  for (int s = 128; s > 0; s >>= 1) {
    if (t < s) red[t] += red[t + s];
    __syncthreads();
  }
  if (t == 0) s_s = red[0] + 1e-16f;
  __syncthreads();
  float sinv = 1.f / s_s;

  for (int i = rs + t; i < re; i += 256)
    scores[i] = expf(scores[i] - m) * sinv;
}

// weighted segment sum: grid (NGRAPH, 4); block (g,q) covers cols
// q*256..q*256+255; 4 waves node-stride-4, lane owns 4 cols (8B loads)
__global__ __launch_bounds__(256) void k_pool2(
    const float* __restrict__ w, const _Float16* __restrict__ x,
    const int* __restrict__ gstart, const int* __restrict__ gend,
    float* __restrict__ pooled) {
  __shared__ float red[3][64][4];
  const int g = blockIdx.x, q = blockIdx.y;
  const int t = threadIdx.x, wv = t >> 6, l = t & 63;
  const int rs = gstart[g], re = gend[g];
  const int cb = q * 256 + 4 * l;

  float acc[4] = {0.f, 0.f, 0.f, 0.f};
  for (int n = rs + wv; n < re; n += 4) {
    const float wn = w[n];
    half4v hv = *(const half4v*)(x + (size_t)n * NPROJ + cb);
#pragma unroll
    for (int j = 0; j < 4; ++j)
      acc[j] = fmaf(wn, (float)hv[j], acc[j]);
  }
  if (wv) {
#pragma unroll
    for (int j = 0; j < 4; ++j) red[wv - 1][l][j] = acc[j];
  }
  __syncthreads();
  if (wv == 0) {
#pragma unroll
    for (int k = 0; k < 3; ++k)
#pragma unroll
      for (int j = 0; j < 4; ++j) acc[j] += red[k][l][j];
    float4 o = make_float4(acc[0], acc[1], acc[2], acc[3]);
    *(float4*)(pooled + (size_t)g * NPROJ + cb) = o;
  }
}

__global__ __launch_bounds__(256) void k_cls1(const float* __restrict__ pooled,
                                              const float* __restrict__ W1,
                                              const float* __restrict__ b1,
                                              float* __restrict__ hid) {
  __shared__ float p[1024];
  int g = blockIdx.y;
  int colc = blockIdx.x * 256 + threadIdx.x;
  for (int k = threadIdx.x; k < 1024; k += 256) p[k] = pooled[(size_t)g * 1024 + k];
  __syncthreads();
  float s = 0.f;
  for (int k = 0; k < 1024; ++k) s = fmaf(p[k], W1[(size_t)k * 512 + colc], s);
  s += b1[colc];
  s = 0.5f * s * (1.f + erff(s * 0.70710678118654752f));
  hid[(size_t)g * 512 + colc] = s;
}

__global__ void k_cls2(const float* __restrict__ hid,
                       const float* __restrict__ W2,
                       const float* __restrict__ b2, float* __restrict__ out) {
  int o = blockIdx.x, g = blockIdx.y, lane = threadIdx.x;
  float s = 0.f;
  for (int k = lane; k < 512; k += 64) s = fmaf(hid[(size_t)g * 512 + k], W2[k * 14 + o], s);
  for (int off = 32; off > 0; off >>= 1) s += __shfl_down(s, off);
  if (lane == 0) out[g * 14 + o] = s + b2[o];
}

// ============================================================
extern "C" void kernel_launch(void* const* d_in, const int* in_sizes, int n_in,
                              void* d_out, int out_size, void* d_ws, size_t ws_size,
                              hipStream_t stream) {
  const float* x_in   = (const float*)d_in[0];
  const int*   eidx   = (const int*)d_in[1];
  const int*   batch  = (const int*)d_in[2];
  const float* proj_W = (const float*)d_in[3];
  const float* proj_b = (const float*)d_in[4];
  const float* gat_W  = (const float*)d_in[5];
  const float* a_src  = (const float*)d_in[6];
  const float* a_dst  = (const float*)d_in[7];
  const float* gat_b  = (const float*)d_in[8];
  const float* gamma  = (const float*)d_in[9];
  const float* beta   = (const float*)d_in[10];
  const float* pW1    = (const float*)d_in[11];
  const float* pb1    = (const float*)d_in[12];
  const float* pW2    = (const float*)d_in[13];
  const float* pb2    = (const float*)d_in[14];
  const float* cW1    = (const float*)d_in[15];
  const float* cb1    = (const float*)d_in[16];
  const float* cW2    = (const float*)d_in[17];
  const float* cb2    = (const float*)d_in[18];
  float* out = (float*)d_out;

  const int N = in_sizes[0] / NPROJ;  // 10000
  const int E = in_sizes[1] / 2;      // 160000
  const int Etot = E + N;
  const int NB = (N + 255) / 256;     // 40 scan blocks

  char* ws = (char*)d_ws;
  size_t off = 0;
  auto alloc = [&](size_t bytes) -> void* {
    void* p = ws + off;
    off = (off + bytes + 255) & ~(size_t)255;
    return p;
  };
  _Float16* xh   = (_Float16*)alloc((size_t)N * NPROJ * 2);
  _Float16* hf   = (_Float16*)alloc((size_t)N * NPROJ * 2);   // f16 h
  float*    hb   = (float*)alloc((size_t)N * NPROJ * 4);      // in-f16 / tb
  _Float16* pjh  = (_Float16*)alloc((size_t)NPROJ * NPROJ * 2);
  _Float16* gwh  = (_Float16*)alloc((size_t)3 * NPROJ * NPROJ * 2);
  _Float16* pwh  = (_Float16*)alloc((size_t)512 * NPROJ * 2);
  float* asb     = (float*)alloc((size_t)N * 4 * 4);
  float* adb     = (float*)alloc((size_t)N * 4 * 4);
  int*   cnt     = (int*)alloc((size_t)N * 4);
  int*   bsum    = (int*)alloc(64 * 4);
  int*   rowst   = (int*)alloc((size_t)(N + 1) * 4);
  int*   cursor  = (int*)alloc((size_t)N * 4);
  int*   ccol    = (int*)alloc((size_t)Etot * 4);
  float* scores  = (float*)alloc((size_t)N * 4);
  int*   gstart  = (int*)alloc(NGRAPH * 4);
  int*   gend    = (int*)alloc(NGRAPH * 4);
  float* pooled  = (float*)alloc((size_t)NGRAPH * NPROJ * 4);
  float* hid     = (float*)alloc((size_t)NGRAPH * 512 * 4);

  const int* esrc = eidx;
  const int* edst = eidx + E;

  // ---- CSR by dst (3-level scan) ----
  k_init_counts<<<NB, 256, 0, stream>>>(cnt, N);
  k_count<<<(E + 255) / 256, 256, 0, stream>>>(edst, cnt, E);
  k_scan1<<<NB, 256, 0, stream>>>(cnt, bsum, N);
  k_scan2<<<1, 64, 0, stream>>>(bsum, NB);
  k_scan3<<<NB, 256, 0, stream>>>(cnt, bsum, rowst, cursor, N, Etot);
  k_fill<<<(E + 255) / 256, 256, 0, stream>>>(esrc, edst, cursor, ccol, E);
  k_fill_self<<<NB, 256, 0, stream>>>(cursor, ccol, N);

  // ---- weight transposes (f16 hi) ----
  k_transT<<<dim3(32, 32), 256, 0, stream>>>(proj_W, pjh, NPROJ, NPROJ);
  for (int i = 0; i < 3; ++i)
    k_transT<<<dim3(32, 32), 256, 0, stream>>>(gat_W + (size_t)i * NPROJ * NPROJ,
                                               gwh + (size_t)i * NPROJ * NPROJ,
                                               NPROJ, NPROJ);
  k_transT<<<dim3(16, 32), 256, 0, stream>>>(pW1, pwh, NPROJ, 512);

  // ---- input f16 (scratch inside hb) + projection ----
  _Float16* inh = (_Float16*)hb;
  k_tof16<<<((N * NPROJ / 8) + 255) / 256, 256, 0, stream>>>(x_in, inh,
                                                             N * NPROJ / 8);
  const int MB = (N + 127) / 128;         // 79  (BM=128 slabs)
  const int mpad8 = (MB + 7) / 8;         // 10
  const dim3 grid8(8 * mpad8 * 8);        // Nc=1024: lgn=3
  const int MB64 = (N + 63) / 64;         // 157 (BM=64 slabs)
  const int mpad8p = (MB64 + 7) / 8;      // 20
  const dim3 grid4(8 * mpad8p * 4);       // Nc=512:  lgn=2, 640 blocks
  gemm_mfma<0, 2, 128><<<grid8, 256, 0, stream>>>(
      inh, pjh, proj_b, nullptr, xh, N, NPROJ, 3, mpad8);

  // ---- 3 GAT layers ----
  for (int i = 0; i < 3; ++i) {
    gemm_mfma<0, 2, 128><<<grid8, 256, 0, stream>>>(
        xh, gwh + (size_t)i * NPROJ * NPROJ,
        nullptr, nullptr, hf, N, NPROJ, 3, mpad8);
    k_alpha<<<(N + 1) / 2, 256, 0, stream>>>(hf, a_src + i * NPROJ,
                                             a_dst + i * NPROJ, asb, adb, N);
    k_aggregate_ln<<<N, 256, 0, stream>>>(hf, asb, adb, rowst, ccol,
                                          gat_b + i * NPROJ, gamma + i * NPROJ,
                                          beta + i * NPROJ, xh);
  }

  // ---- attention pooling ----
  float* tb = hb;  // N x 512 f32
  gemm_mfma<1, 0, 64><<<grid4, 256, 0, stream>>>(
      xh, pwh, pb1, tb, nullptr, N, 512, 2, mpad8p);
  k_scores<<<N, 64, 0, stream>>>(tb, pW2, pb2, scores, N);
  k_grange_init<<<1, 64, 0, stream>>>(gstart, gend, N);
  k_grange_mark<<<NB, 256, 0, stream>>>(batch, gstart, gend, N);
  k_poolw<<<NGRAPH, 256, 0, stream>>>(scores, gstart, gend);
  k_pool2<<<dim3(NGRAPH, 4), 256, 0, stream>>>(scores, xh, gstart, gend,
                                               pooled);

  // ---- classifier ----
  k_cls1<<<dim3(2, NGRAPH), 256, 0, stream>>>(pooled, cW1, cb1, hid);
  k_cls2<<<dim3(14, NGRAPH), 64, 0, stream>>>(hid, cW2, cb2, out);
}